// Round 11
// baseline (3466.451 us; speedup 1.0000x reference)
//
#include <hip/hip_runtime.h>
#include <cmath>

typedef unsigned short ushort_t;
typedef __attribute__((ext_vector_type(8))) short bf16x8;
typedef __attribute__((ext_vector_type(4))) float f32x4;

// Problem constants (B=2, C=64, H=W=256)
static constexpr int Bn   = 2;
static constexpr int Hn   = 256;
static constexpr int Wn   = 256;
static constexpr int HW   = Hn * Wn;          // 65536
static constexpr int CHW  = 64 * HW;          // 4194304
static constexpr int NCHW = Bn * CHW;         // 8388608
static constexpr int NPIX = Bn * HW;          // 131072
static constexpr float EPSv = 1e-5f;
static constexpr float INV_N = 1.0f / 131072.0f;   // BN count = B*H*W
static constexpr int NSLOT = 64;              // stats slot replication (anti-contention)
static constexpr int STSLOT = NSLOT * 128;    // floats per layer stats region
static constexpr int WFL = 73728;             // ushorts per weight-fragment layer slot

// bf16 round-to-nearest-even (no NaN inputs in this net)
__device__ inline uint32_t bf16_rne(float f) {
  uint32_t u = __float_as_uint(f);
  return (u + 0x7FFFu + ((u >> 16) & 1u)) >> 16;
}
__device__ inline void split_hl(float v, uint32_t& h, uint32_t& l) {
  h = bf16_rne(v);
  l = bf16_rne(v - __uint_as_float(h << 16)) & 0xFFFFu;
}
__device__ inline bf16x8 lds_ld16(const ushort_t* p) {   // 2x ds_read_b64
  union { bf16x8 v; uint2 u[2]; } r;
  r.u[0] = *(const uint2*)p;
  r.u[1] = *(const uint2*)(p + 4);
  return r.v;
}

// ---------------------------------------------------------------------------
__global__ void transpose_w_kernel(const float* __restrict__ in, float* __restrict__ out,
                                   int NB, int OC, int IC, int K) {
  int total = NB * OC * IC * K;
  for (int i = blockIdx.x * blockDim.x + threadIdx.x; i < total; i += gridDim.x * blockDim.x) {
    int k  = i % K;
    int t  = i / K;
    int ic = t % IC; t /= IC;
    int oc = t % OC;
    int nb = t / OC;
    out[(((size_t)nb * IC + ic) * K + k) * OC + oc] = in[i];
  }
}

// ---------------------------------------------------------------------------
// Weight fragment prep: w[oc][ic][3][3] f32 -> MFMA B-frag order, bf16 hi/lo.
__global__ void prep_wfrag(const float* __restrict__ w, ushort_t* __restrict__ out,
                           int NGp, int ocreal, int wlstride, int olstride) {
  int layer = blockIdx.y;
  int elems = 9 * 2 * NGp * 64 * 8;
  int idx = blockIdx.x * 256 + threadIdx.x;
  if (idx >= elems) return;
  int j = idx & 7, lane = (idx >> 3) & 63;
  int rest = idx >> 9;
  int g = rest % NGp; rest /= NGp;
  int ih = rest & 1, tap = rest >> 1;
  int oc = g * 16 + (lane & 15);
  int ic = ih * 32 + (lane >> 4) * 8 + j;
  float v = 0.0f;
  if (oc < ocreal) v = w[(size_t)layer * wlstride + (oc * 64 + ic) * 9 + tap];
  uint32_t hi, lo;
  split_hl(v, hi, lo);
  out[(size_t)layer * olstride + idx] = (ushort_t)hi;
  out[(size_t)layer * olstride + elems + idx] = (ushort_t)lo;
}

// ---------------------------------------------------------------------------
__global__ void prep_kernel(const float* __restrict__ LowDEM, const float* __restrict__ Point_Ele,
                            const float* __restrict__ Slope, const float* __restrict__ Distance,
                            const float* __restrict__ Level, const float* __restrict__ w0,
                            const float* __restrict__ b0, float* __restrict__ x0) {
  int i = blockIdx.x * blockDim.x + threadIdx.x;
  if (i >= NPIX) return;
  float lv  = Level[i];
  float err = w0[0] * Slope[i] + w0[1] * Distance[i] + w0[2] * lv + b0[0];
  float lm  = (lv != 0.0f) ? 1.0f : 0.0f;
  x0[i] = LowDEM[i] * (1.0f - lm) + Point_Ele[i] + err * lm;
}

// ---------------------------------------------------------------------------
__global__ __launch_bounds__(256, 2)
void conv9x9_kernel(const float* __restrict__ in, const float* __restrict__ wT,
                    const float* __restrict__ bias, float* __restrict__ out) {
  const int tx = threadIdx.x & 15, ty = threadIdx.x >> 4;
  const int w0 = blockIdx.x * 16, h0 = blockIdx.y * 16, b = blockIdx.z;
  __shared__ float lds[24 * 24];
  for (int idx = threadIdx.x; idx < 576; idx += 256) {
    int yy = idx / 24, xx = idx - yy * 24;
    int gy = h0 + yy - 4, gx = w0 + xx - 4;
    float v = 0.0f;
    if ((unsigned)gy < 256u && (unsigned)gx < 256u) v = in[b * HW + gy * 256 + gx];
    lds[idx] = v;
  }
  __syncthreads();
  float acc[64];
#pragma unroll
  for (int o = 0; o < 64; o++) acc[o] = 0.0f;
#pragma unroll 1
  for (int i = 0; i < 9; i++) {
#pragma unroll
    for (int j = 0; j < 9; j++) {
      float v = lds[(ty + i) * 24 + tx + j];
      const float* wp = wT + (i * 9 + j) * 64;   // uniform -> s_load
#pragma unroll
      for (int o = 0; o < 64; o++) acc[o] = fmaf(v, wp[o], acc[o]);
    }
  }
  const int p = (h0 + ty) * 256 + (w0 + tx);
  float* op = out + (size_t)b * CHW + p;
#pragma unroll
  for (int o = 0; o < 64; o++) op[o * HW] = acc[o] + bias[o];
}

// ---------------------------------------------------------------------------
// MFMA conv3x3, R11: OCCUPANCY experiment. R8-R10 tested B-latency hiding,
// A-read width, and MFMA:load intensity — all neutral — while
// __launch_bounds__(256,3) silently capped residency at 3 blocks/CU the
// whole time. R11: 16x4 tile (29.4 KB planes) + unioned scratch (preamble
// slot-sums and epilogue stats-reduce share one 2 KB buffer) -> 31.9 KB
// total -> 5 blocks/CU with __launch_bounds__(256,5) (20 waves/CU, 1.67x).
// MODE 0 plain / 1 relu(bn) / 2 bn+skip (WRITEY: materialize y). INHWC:
// pixel-major input. Separated hi/lo planes (R9), batched B-loads (R7).
// ---------------------------------------------------------------------------
template <int NG, int MODE, int STATS, int OCLIM, int HASBIAS, int WRITEY, int INHWC>
__global__ __launch_bounds__(256, 5)
void mfma_conv3(const float* __restrict__ in, const float* __restrict__ skip,
                const ushort_t* __restrict__ wf,
                const float* __restrict__ bias, const float* __restrict__ stats_in,
                const float* __restrict__ gg, const float* __restrict__ be,
                float* __restrict__ stats_out, float* __restrict__ yout,
                float* __restrict__ out) {
  const int tid  = threadIdx.x;
  const int lane = tid & 63, wid = tid >> 6;
  const int m = lane & 15, quad = lane >> 4;
  const int x0 = blockIdx.x * 16, y0 = blockIdx.y * 4, b = blockIdx.z;
  constexpr int WT = 2 * NG * 64 * 8;          // ushorts per tap per plane
  __shared__ __align__(16) ushort_t xh[108 * 68];   // hi plane, [spat][ch]
  __shared__ __align__(16) ushort_t xl[108 * 68];   // lo plane
  __shared__ float s_sc[MODE ? 64 : 1], s_sh[MODE ? 64 : 1];
  __shared__ float scr[(MODE || STATS) ? 512 : 1];  // preamble slot-sums / stats reduce
  if (MODE) {
    int c = tid & 63, part = tid >> 6;
    float sum = 0.0f, sq = 0.0f;
    for (int sl = part; sl < NSLOT; sl += 4) {   // 4-way parallel slot sum
      sum += stats_in[sl * 128 + c];
      sq  += stats_in[sl * 128 + 64 + c];
    }
    scr[part * 64 + c] = sum;
    scr[256 + part * 64 + c] = sq;
    __syncthreads();
    if (tid < 64) {
      float s4 = scr[c] + scr[64 + c] + scr[128 + c] + scr[192 + c];
      float q4 = scr[256 + c] + scr[320 + c] + scr[384 + c] + scr[448 + c];
      float mn = s4 * INV_N, var = q4 * INV_N - mn * mn;
      float s = gg[c] * rsqrtf(var + EPSv);
      s_sc[c] = s;
      s_sh[c] = be[c] - mn * s;
    }
    __syncthreads();
  }
  const float* inb = in + (size_t)b * CHW;
  const float* skb = MODE == 2 ? skip + (size_t)b * CHW : nullptr;
  float* ytb = WRITEY ? yout + (size_t)b * CHW : nullptr;
  uint32_t* xh32 = (uint32_t*)xh;              // row stride 34 dwords
  uint32_t* xl32 = (uint32_t*)xl;
#pragma unroll
  for (int t = 0; t < 14; t++) {
    int idx = t * 256 + tid;                   // 3456 = 108 spat * 32 ic-pairs
    if (idx < 3456) {
      int r, icp;
      if (INHWC) { icp = idx & 31; r = idx >> 5; }   // tid-contig ic -> coalesced HWC
      else       { r = idx % 108; icp = idx / 108; } // tid-contig px -> coalesced NCHW
      int row = r / 18, col = r - row * 18;
      int gy = y0 - 1 + row, gx = x0 - 1 + col;
      float v0 = 0.0f, v1 = 0.0f;
      if ((unsigned)gy < 256u && (unsigned)gx < 256u) {
        int ic = icp * 2;
        if (INHWC) {
          float2 vv = *(const float2*)&inb[(size_t)(gy * 256 + gx) * 64 + ic];
          v0 = vv.x; v1 = vv.y;
        } else {
          v0 = inb[ic * HW + gy * 256 + gx];
          v1 = inb[(ic + 1) * HW + gy * 256 + gx];
        }
        if (MODE == 1) {
          v0 = fmaxf(fmaf(v0, s_sc[ic], s_sh[ic]), 0.0f);
          v1 = fmaxf(fmaf(v1, s_sc[ic + 1], s_sh[ic + 1]), 0.0f);
        }
        if (MODE == 2) {
          v0 = fmaf(v0, s_sc[ic], s_sh[ic]) + skb[ic * HW + gy * 256 + gx];
          v1 = fmaf(v1, s_sc[ic + 1], s_sh[ic + 1]) + skb[(ic + 1) * HW + gy * 256 + gx];
          if (WRITEY && row >= 1 && row <= 4 && col >= 1 && col <= 16) {
            ytb[ic * HW + gy * 256 + gx] = v0;
            ytb[(ic + 1) * HW + gy * 256 + gx] = v1;
          }
        }
      }
      uint32_t h0, l0, h1, l1;
      split_hl(v0, h0, l0);
      split_hl(v1, h1, l1);
      xh32[r * 34 + icp] = h0 | (h1 << 16);
      xl32[r * 34 + icp] = l0 | (l1 << 16);
    }
  }
  __syncthreads();                             // the ONLY barrier before epilogue
  f32x4 acc[NG];
#pragma unroll
  for (int g = 0; g < NG; g++) acc[g] = (f32x4){0.0f, 0.0f, 0.0f, 0.0f};

  const bf16x8* wfh = (const bf16x8*)wf;                 // hi plane, frag-ordered
  const bf16x8* wfl = (const bf16x8*)(wf + 9 * WT);      // lo plane

#pragma unroll 1
  for (int tap = 0; tap < 9; tap++) {
    bf16x8 bh[2][NG], bl[2][NG];
#pragma unroll
    for (int ih = 0; ih < 2; ih++)
#pragma unroll
      for (int g = 0; g < NG; g++) {
        int fi = ((tap * 2 + ih) * NG + g) * 64 + lane;
        bh[ih][g] = wfh[fi];
        bl[ih][g] = wfl[fi];
      }
    const int dy = tap / 3 - 1, dx = tap % 3 - 1;
    const int spat = (wid + dy + 1) * 18 + (m + dx + 1);
#pragma unroll
    for (int ih = 0; ih < 2; ih++) {
      const int base = spat * 68 + ih * 32 + quad * 8;
      bf16x8 ah = lds_ld16(xh + base);
      bf16x8 al = lds_ld16(xl + base);
#pragma unroll
      for (int g = 0; g < NG; g++) {
        acc[g] = __builtin_amdgcn_mfma_f32_16x16x32_bf16(ah, bh[ih][g], acc[g], 0, 0, 0);
        acc[g] = __builtin_amdgcn_mfma_f32_16x16x32_bf16(al, bh[ih][g], acc[g], 0, 0, 0);
        acc[g] = __builtin_amdgcn_mfma_f32_16x16x32_bf16(ah, bl[ih][g], acc[g], 0, 0, 0);
      }
    }
  }
  // epilogue: D[row=quad*4+r][col=lane&15] -> pixel (y0+wid, x0+quad*4+r), oc=g*16+m
  const int py = y0 + wid;
  float* ob = out + (size_t)b * OCLIM * HW + py * 256 + x0 + quad * 4;
#pragma unroll
  for (int g = 0; g < NG; g++) {
    int oc = g * 16 + m;
    if (oc < OCLIM) {
      float bv = HASBIAS ? bias[oc] : 0.0f;
#pragma unroll
      for (int r = 0; r < 4; r++) ob[oc * HW + r] = acc[g][r] + bv;
    }
    if (STATS) {
      float s  = acc[g][0] + acc[g][1] + acc[g][2] + acc[g][3];
      float s2 = acc[g][0] * acc[g][0] + acc[g][1] * acc[g][1] +
                 acc[g][2] * acc[g][2] + acc[g][3] * acc[g][3];
      s  += __shfl_xor(s, 16, 64);  s  += __shfl_xor(s, 32, 64);
      s2 += __shfl_xor(s2, 16, 64); s2 += __shfl_xor(s2, 32, 64);
      if (lane < 16) {
        scr[(0 * 4 + wid) * 64 + g * 16 + lane] = s;
        scr[(1 * 4 + wid) * 64 + g * 16 + lane] = s2;
      }
    }
  }
  if (STATS) {
    __syncthreads();
    if (tid < 128) {
      int oc = tid & 63, which = tid >> 6;
      float tot = scr[(which * 4 + 0) * 64 + oc] + scr[(which * 4 + 1) * 64 + oc] +
                  scr[(which * 4 + 2) * 64 + oc] + scr[(which * 4 + 3) * 64 + oc];
      int slot = (blockIdx.y * 16 + blockIdx.x) & (NSLOT - 1);
      atomicAdd(&stats_out[slot * 128 + which * 64 + oc], tot);
    }
  }
}

// ---------------------------------------------------------------------------
__global__ void bn_apply_add_kernel(const float* __restrict__ t, const float* __restrict__ stats,
                                    const float* __restrict__ g, const float* __restrict__ be,
                                    const float* __restrict__ skip, float* __restrict__ out) {
  __shared__ float s_sc[64], s_sh[64];
  if (threadIdx.x < 64) {
    int c = threadIdx.x;
    float sum = 0.0f, sq = 0.0f;
    for (int sl = 0; sl < NSLOT; sl++) {
      sum += stats[sl * 128 + c];
      sq  += stats[sl * 128 + 64 + c];
    }
    float m   = sum * INV_N;
    float var = sq * INV_N - m * m;
    float s   = g[c] * rsqrtf(var + EPSv);
    s_sc[c] = s;
    s_sh[c] = be[c] - m * s;
  }
  __syncthreads();
  const float4* t4 = (const float4*)t;
  const float4* k4 = (const float4*)skip;
  float4* o4 = (float4*)out;
  const int n4 = NCHW / 4;
  for (int i = blockIdx.x * blockDim.x + threadIdx.x; i < n4; i += gridDim.x * blockDim.x) {
    int c = (i >> 14) & 63;
    float s = s_sc[c], h = s_sh[c];
    float4 v = t4[i], kk = k4[i], r;
    r.x = fmaf(v.x, s, h) + kk.x;
    r.y = fmaf(v.y, s, h) + kk.y;
    r.z = fmaf(v.z, s, h) + kk.z;
    r.w = fmaf(v.w, s, h) + kk.w;
    o4[i] = r;
  }
}

// ---------------------------------------------------------------------------
// NCHW -> NHWC transpose (LDS-tiled, both sides coalesced, 64x65 pad).
// ---------------------------------------------------------------------------
__global__ __launch_bounds__(256, 4)
void nchw_to_nhwc(const float* __restrict__ in, float* __restrict__ out) {
  __shared__ float t[64][65];
  const int blk = blockIdx.x;            // 2048 = NPIX/64
  const int b = blk >> 10;
  const int p0 = (blk & 1023) * 64;
  const float* ib = in + (size_t)b * CHW;
  float* ob = out + (size_t)b * CHW;
#pragma unroll
  for (int i = 0; i < 16; i++) {
    int idx = i * 256 + threadIdx.x;
    int c = idx >> 6, p = idx & 63;
    t[c][p] = ib[c * HW + p0 + p];
  }
  __syncthreads();
#pragma unroll
  for (int i = 0; i < 16; i++) {
    int idx = i * 256 + threadIdx.x;
    int p = idx >> 6, c = idx & 63;
    ob[(size_t)(p0 + p) * 64 + c] = t[c][p];
  }
}

// ---------------------------------------------------------------------------
// Deformable conv on MFMA, HWC input (R9 form): separated hi/lo planes, 128B
// rows + 32B-chunk XOR swizzle, double-buffered, 1 barrier/tap. R11: bounds
// raised (256,4)->(256,5); 5 x 32.8 KB = 160 KB exactly fits the LDS pool.
// FINAL: OC=1, fuse dc4 bias + conv4, write d_out planar.
// ---------------------------------------------------------------------------
template <int NG, int FINAL>
__global__ __launch_bounds__(256, 5)
void dcn_mfma(const float* __restrict__ xhwc, const float* __restrict__ om,
              const ushort_t* __restrict__ wf, const float* __restrict__ bias,
              const float* __restrict__ c4w, const float* __restrict__ c4b,
              float* __restrict__ out) {
  const int tid  = threadIdx.x;
  const int lane = tid & 63, wid = tid >> 6;
  const int m = lane & 15, quad = lane >> 4;
  const int x0 = blockIdx.x * 16, y0 = blockIdx.y * 4, b = blockIdx.z;
  constexpr int WT = 2 * NG * 64 * 8;
  __shared__ __align__(16) ushort_t sh[2][64 * 64];   // hi plane per buffer, 8 KB
  __shared__ __align__(16) ushort_t sl[2][64 * 64];   // lo plane
  const int gpx = tid & 63, cg = tid >> 6;     // gather role: pixel, 16-ch group
  const int gpy = y0 + (gpx >> 4), gxx = x0 + (gpx & 15);
  const float* xb  = xhwc + (size_t)b * CHW;
  const float* omb = om + (size_t)b * 27 * HW + gpy * 256 + gxx;
  const int wchunk = (cg ^ (gpx & 3)) * 16;    // swizzled 32B-chunk base (ushorts)

  auto gather = [&](int tap, int buf) {
    float dyv = omb[tap * HW];
    float dxv = omb[(9 + tap) * HW];
    float mo  = omb[(18 + tap) * HW];
    float mk  = 1.0f / (1.0f + __expf(-mo));
    float ys = fminf(fmaxf((float)(gpy + tap / 3 - 1) + dyv, -2.0f), 258.0f);
    float xs = fminf(fmaxf((float)(gxx + tap % 3 - 1) + dxv, -2.0f), 258.0f);
    float y0f = floorf(ys), x0f = floorf(xs);
    float wy = ys - y0f, wx = xs - x0f;
    int yi = (int)y0f, xi = (int)x0f;
    float vy0 = ((unsigned)yi       < 256u) ? 1.0f : 0.0f;
    float vy1 = ((unsigned)(yi + 1) < 256u) ? 1.0f : 0.0f;
    float vx0 = ((unsigned)xi       < 256u) ? 1.0f : 0.0f;
    float vx1 = ((unsigned)(xi + 1) < 256u) ? 1.0f : 0.0f;
    int cy0 = min(max(yi, 0), 255), cy1 = min(max(yi + 1, 0), 255);
    int cx0 = min(max(xi, 0), 255), cx1 = min(max(xi + 1, 0), 255);
    float W00 = (1.0f - wy) * (1.0f - wx) * mk * vy0 * vx0;
    float W01 = (1.0f - wy) * wx * mk * vy0 * vx1;
    float W10 = wy * (1.0f - wx) * mk * vy1 * vx0;
    float W11 = wy * wx * mk * vy1 * vx1;
    const float* p00 = xb + (size_t)(cy0 * 256 + cx0) * 64 + cg * 16;
    const float* p01 = xb + (size_t)(cy0 * 256 + cx1) * 64 + cg * 16;
    const float* p10 = xb + (size_t)(cy1 * 256 + cx0) * 64 + cg * 16;
    const float* p11 = xb + (size_t)(cy1 * 256 + cx1) * 64 + cg * 16;
#pragma unroll
    for (int q4 = 0; q4 < 4; q4++) {
      float4 a  = ((const float4*)p00)[q4];
      float4 b2 = ((const float4*)p01)[q4];
      float4 c2 = ((const float4*)p10)[q4];
      float4 d2 = ((const float4*)p11)[q4];
      float s0 = W00 * a.x + W01 * b2.x + W10 * c2.x + W11 * d2.x;
      float s1 = W00 * a.y + W01 * b2.y + W10 * c2.y + W11 * d2.y;
      float s2 = W00 * a.z + W01 * b2.z + W10 * c2.z + W11 * d2.z;
      float s3 = W00 * a.w + W01 * b2.w + W10 * c2.w + W11 * d2.w;
      uint32_t h0, l0, h1, l1, h2, l2, h3, l3;
      split_hl(s0, h0, l0); split_hl(s1, h1, l1);
      split_hl(s2, h2, l2); split_hl(s3, h3, l3);
      int wi = gpx * 64 + wchunk + q4 * 4;     // 8B-aligned
      *(uint2*)&sh[buf][wi] = make_uint2(h0 | (h1 << 16), h2 | (h3 << 16));
      *(uint2*)&sl[buf][wi] = make_uint2(l0 | (l1 << 16), l2 | (l3 << 16));
    }
  };

  f32x4 acc[NG];
#pragma unroll
  for (int g = 0; g < NG; g++) acc[g] = (f32x4){0.0f, 0.0f, 0.0f, 0.0f};
  const bf16x8* wfh = (const bf16x8*)wf;
  const bf16x8* wfl = (const bf16x8*)(wf + 9 * WT);
  const int px = wid * 16 + m;                 // this lane's A-row pixel

  gather(0, 0);
  __syncthreads();
#pragma unroll 1
  for (int tap = 0; tap < 9; tap++) {
    const int cur = tap & 1;
    if (tap < 8) gather(tap + 1, cur ^ 1);     // overlaps MFMAs below
#pragma unroll
    for (int ih = 0; ih < 2; ih++) {
      const int c = ih * 2 + (quad >> 1), h = quad & 1;
      const int ri = px * 64 + ((c ^ (px & 3)) * 16) + h * 8;   // 16B-aligned
      bf16x8 ah = *(const bf16x8*)&sh[cur][ri];
      bf16x8 al = *(const bf16x8*)&sl[cur][ri];
#pragma unroll
      for (int g = 0; g < NG; g++) {
        int fi = ((tap * 2 + ih) * NG + g) * 64 + lane;
        bf16x8 bh = wfh[fi], bl = wfl[fi];
        acc[g] = __builtin_amdgcn_mfma_f32_16x16x32_bf16(ah, bh, acc[g], 0, 0, 0);
        acc[g] = __builtin_amdgcn_mfma_f32_16x16x32_bf16(al, bh, acc[g], 0, 0, 0);
        acc[g] = __builtin_amdgcn_mfma_f32_16x16x32_bf16(ah, bl, acc[g], 0, 0, 0);
      }
    }
    __syncthreads();   // writes to buf^1 and reads of cur both done
  }
  const int py = y0 + wid;
  if (FINAL) {
    if (m == 0) {
      float* op = out + (size_t)b * HW + py * 256 + x0 + quad * 4;
#pragma unroll
      for (int r = 0; r < 4; r++) op[r] = c4w[0] * (acc[0][r] + bias[0]) + c4b[0];
    }
  } else {
    float* ob = out + (size_t)b * CHW + ((size_t)py * 256 + x0 + quad * 4) * 64 + m;
#pragma unroll
    for (int g = 0; g < NG; g++)
#pragma unroll
      for (int r = 0; r < 4; r++)
        ob[r * 64 + g * 16] = fmaxf(acc[g][r] + bias[g * 16 + m], 0.0f);
  }
}

// ---------------------------------------------------------------------------
extern "C" void kernel_launch(void* const* d_in, const int* in_sizes, int n_in,
                              void* d_out, int out_size, void* d_ws, size_t ws_size,
                              hipStream_t stream) {
  const float* LowDEM    = (const float*)d_in[0];
  const float* Point_Ele = (const float*)d_in[1];
  const float* Slope     = (const float*)d_in[2];
  const float* Distance  = (const float*)d_in[3];
  const float* Level     = (const float*)d_in[4];
  const float* conv0_w   = (const float*)d_in[5];
  const float* conv0_b   = (const float*)d_in[6];
  const float* conv1_w   = (const float*)d_in[7];
  const float* conv1_b   = (const float*)d_in[8];
  const float* rb_w1     = (const float*)d_in[9];
  const float* rb_g1     = (const float*)d_in[11];
  const float* rb_be1    = (const float*)d_in[12];
  const float* rb_w2     = (const float*)d_in[13];
  const float* rb_g2     = (const float*)d_in[15];
  const float* rb_be2    = (const float*)d_in[16];
  const float* conv2_w   = (const float*)d_in[17];
  const float* bn2_g     = (const float*)d_in[19];
  const float* bn2_be    = (const float*)d_in[20];
  const float* dc2_w     = (const float*)d_in[21];
  const float* dc2_b     = (const float*)d_in[22];
  const float* dc2_ow    = (const float*)d_in[23];
  const float* dc2_ob    = (const float*)d_in[24];
  const float* dc3_w     = (const float*)d_in[25];
  const float* dc3_b     = (const float*)d_in[26];
  const float* dc3_ow    = (const float*)d_in[27];
  const float* dc3_ob    = (const float*)d_in[28];
  const float* dc4_w     = (const float*)d_in[29];
  const float* dc4_b     = (const float*)d_in[30];
  const float* dc4_ow    = (const float*)d_in[31];
  const float* dc4_ob    = (const float*)d_in[32];
  const float* conv4_w   = (const float*)d_in[33];
  const float* conv4_b   = (const float*)d_in[34];

  // small region first, then big buffers
  float* x0   = (float*)d_ws;             // 131072
  float* T1   = x0 + NPIX;                // 5184
  ushort_t* WF = (ushort_t*)(T1 + 5184);  // 39 * WFL ushorts
  float* stats = (float*)(WF + 39 * WFL); // 33 * STSLOT floats
  float* big   = stats + 33 * STSLOT;
  size_t used_small = (size_t)((char*)big - (char*)d_ws);
  bool fused = ws_size >= used_small + 5ull * NCHW * sizeof(float);

  float* bufX  = big;                     // X (conv9x9 out; skip for bn2)
  float* bufT  = bufX + NCHW;             // t1 / conv2 out / offset-conv out
  float* bufT2 = bufT + NCHW;             // t2
  float* yA    = bufT2 + NCHW;            // y ping
  float* yB    = fused ? yA + NCHW : yA;  // y pong (legacy: aliases yA)

  hipMemsetAsync(stats, 0, 33 * STSLOT * sizeof(float), stream);

  transpose_w_kernel<<<32, 256, 0, stream>>>(conv1_w, T1, 1, 64, 1, 81);

  prep_wfrag<<<dim3(144, 16), 256, 0, stream>>>(rb_w1,   WF,            4, 64, 36864, WFL);
  prep_wfrag<<<dim3(144, 16), 256, 0, stream>>>(rb_w2,   WF + 16 * WFL, 4, 64, 36864, WFL);
  prep_wfrag<<<dim3(144, 1),  256, 0, stream>>>(conv2_w, WF + 32 * WFL, 4, 64, 36864, WFL);
  prep_wfrag<<<dim3(72, 1),   256, 0, stream>>>(dc2_ow,  WF + 33 * WFL, 2, 27, 15552, WFL);
  prep_wfrag<<<dim3(72, 1),   256, 0, stream>>>(dc3_ow,  WF + 34 * WFL, 2, 27, 15552, WFL);
  prep_wfrag<<<dim3(72, 1),   256, 0, stream>>>(dc4_ow,  WF + 35 * WFL, 2, 27, 15552, WFL);
  prep_wfrag<<<dim3(144, 1),  256, 0, stream>>>(dc2_w,   WF + 36 * WFL, 4, 64, 36864, WFL);
  prep_wfrag<<<dim3(144, 1),  256, 0, stream>>>(dc3_w,   WF + 37 * WFL, 4, 64, 36864, WFL);
  prep_wfrag<<<dim3(36, 1),   256, 0, stream>>>(dc4_w,   WF + 38 * WFL, 1, 1, 576, WFL);

  prep_kernel<<<(NPIX + 255) / 256, 256, 0, stream>>>(LowDEM, Point_Ele, Slope, Distance,
                                                      Level, conv0_w, conv0_b, x0);

  dim3 grid16(16, 16, 2);   // conv9x9
  dim3 gmf(16, 64, 2);      // mfma conv3x3 / dcn_mfma (16x4 pixel tiles)

  conv9x9_kernel<<<grid16, 256, 0, stream>>>(x0, T1, conv1_b, bufX);   // X in bufX

  if (fused) {
    mfma_conv3<4, 0, 1, 64, 0, 0, 0><<<gmf, 256, 0, stream>>>(
        bufX, nullptr, WF, nullptr, nullptr, nullptr, nullptr,
        stats, nullptr, bufT);
    mfma_conv3<4, 1, 1, 64, 0, 0, 0><<<gmf, 256, 0, stream>>>(
        bufT, nullptr, WF + 16 * WFL, nullptr, stats,
        rb_g1, rb_be1, stats + STSLOT, nullptr, bufT2);
    for (int i = 1; i < 16; i++) {
      const float* skp = (i == 1) ? bufX : ((i & 1) ? yB : yA);  // y_{i-2}
      float* yo = (i & 1) ? yA : yB;                              // y_{i-1}
      mfma_conv3<4, 2, 1, 64, 0, 1, 0><<<gmf, 256, 0, stream>>>(
          bufT2, skp, WF + (size_t)i * WFL, nullptr, stats + (2 * i - 1) * STSLOT,
          rb_g2 + (i - 1) * 64, rb_be2 + (i - 1) * 64,
          stats + (2 * i) * STSLOT, yo, bufT);
      mfma_conv3<4, 1, 1, 64, 0, 0, 0><<<gmf, 256, 0, stream>>>(
          bufT, nullptr, WF + (size_t)(16 + i) * WFL, nullptr, stats + (2 * i) * STSLOT,
          rb_g1 + i * 64, rb_be1 + i * 64, stats + (2 * i + 1) * STSLOT, nullptr, bufT2);
    }
    mfma_conv3<4, 2, 1, 64, 0, 0, 0><<<gmf, 256, 0, stream>>>(
        bufT2, yA, WF + (size_t)32 * WFL, nullptr, stats + 31 * STSLOT,
        rb_g2 + 15 * 64, rb_be2 + 15 * 64, stats + 32 * STSLOT, nullptr, bufT);
  } else {
    float* bufY = yA;
    for (int i = 0; i < 16; i++) {
      const float* src = (i == 0) ? bufX : bufY;
      mfma_conv3<4, 0, 1, 64, 0, 0, 0><<<gmf, 256, 0, stream>>>(
          src, nullptr, WF + (size_t)i * WFL, nullptr, nullptr, nullptr, nullptr,
          stats + (2 * i) * STSLOT, nullptr, bufT);
      mfma_conv3<4, 1, 1, 64, 0, 0, 0><<<gmf, 256, 0, stream>>>(
          bufT, nullptr, WF + (size_t)(16 + i) * WFL, nullptr, stats + (2 * i) * STSLOT,
          rb_g1 + i * 64, rb_be1 + i * 64, stats + (2 * i + 1) * STSLOT, nullptr, bufT2);
      bn_apply_add_kernel<<<2048, 256, 0, stream>>>(bufT2, stats + (2 * i + 1) * STSLOT,
                                                    rb_g2 + i * 64, rb_be2 + i * 64, src, bufY);
    }
    mfma_conv3<4, 0, 1, 64, 0, 0, 0><<<gmf, 256, 0, stream>>>(
        bufY, nullptr, WF + (size_t)32 * WFL, nullptr, nullptr, nullptr, nullptr,
        stats + 32 * STSLOT, nullptr, bufT);
  }

  // x = bn(conv2_out) + X  -> bufX (planar)
  bn_apply_add_kernel<<<2048, 256, 0, stream>>>(bufT, stats + 32 * STSLOT, bn2_g, bn2_be,
                                                bufX, bufX);

  // HWC mirror of x for the dcn gather
  float* xT    = fused ? yB : yA;     // free by now
  float* d2out = fused ? yA : bufT2;  // dc2 output (HWC)
  float* d3out = fused ? bufT2 : yA;  // dc3 output (HWC)
  nchw_to_nhwc<<<2048, 256, 0, stream>>>(bufX, xT);

  // dc2
  mfma_conv3<2, 0, 0, 27, 1, 0, 0><<<gmf, 256, 0, stream>>>(
      bufX, nullptr, WF + (size_t)33 * WFL, dc2_ob, nullptr, nullptr, nullptr,
      nullptr, nullptr, bufT);
  dcn_mfma<4, 0><<<gmf, 256, 0, stream>>>(xT, bufT, WF + (size_t)36 * WFL, dc2_b,
                                          nullptr, nullptr, d2out);
  // dc3
  mfma_conv3<2, 0, 0, 27, 1, 0, 1><<<gmf, 256, 0, stream>>>(
      d2out, nullptr, WF + (size_t)34 * WFL, dc3_ob, nullptr, nullptr, nullptr,
      nullptr, nullptr, bufT);
  dcn_mfma<4, 0><<<gmf, 256, 0, stream>>>(d2out, bufT, WF + (size_t)37 * WFL, dc3_b,
                                          nullptr, nullptr, d3out);
  // dc4 + conv4 -> d_out
  mfma_conv3<2, 0, 0, 27, 1, 0, 1><<<gmf, 256, 0, stream>>>(
      d3out, nullptr, WF + (size_t)35 * WFL, dc4_ob, nullptr, nullptr, nullptr,
      nullptr, nullptr, bufT);
  dcn_mfma<1, 1><<<gmf, 256, 0, stream>>>(d3out, bufT, WF + (size_t)38 * WFL, dc4_b,
                                          conv4_w, conv4_b, (float*)d_out);
}

// Round 12
// 3278.899 us; speedup vs baseline: 1.0572x; 1.0572x over previous
//
#include <hip/hip_runtime.h>
#include <cmath>

typedef unsigned short ushort_t;
typedef __attribute__((ext_vector_type(8))) short bf16x8;
typedef __attribute__((ext_vector_type(4))) float f32x4;

// Problem constants (B=2, C=64, H=W=256)
static constexpr int Bn   = 2;
static constexpr int Hn   = 256;
static constexpr int Wn   = 256;
static constexpr int HW   = Hn * Wn;          // 65536
static constexpr int CHW  = 64 * HW;          // 4194304
static constexpr int NCHW = Bn * CHW;         // 8388608
static constexpr int NPIX = Bn * HW;          // 131072
static constexpr float EPSv = 1e-5f;
static constexpr float INV_N = 1.0f / 131072.0f;   // BN count = B*H*W
static constexpr int NSLOT = 64;              // stats slot replication (anti-contention)
static constexpr int STSLOT = NSLOT * 128;    // floats per layer stats region
static constexpr int WFL = 73728;             // ushorts per weight-fragment layer slot

// bf16 round-to-nearest-even (no NaN inputs in this net)
__device__ inline uint32_t bf16_rne(float f) {
  uint32_t u = __float_as_uint(f);
  return (u + 0x7FFFu + ((u >> 16) & 1u)) >> 16;
}
__device__ inline void split_hl(float v, uint32_t& h, uint32_t& l) {
  h = bf16_rne(v);
  l = bf16_rne(v - __uint_as_float(h << 16)) & 0xFFFFu;
}
__device__ inline bf16x8 lds_ld16(const ushort_t* p) {   // 2x ds_read_b64
  union { bf16x8 v; uint2 u[2]; } r;
  r.u[0] = *(const uint2*)p;
  r.u[1] = *(const uint2*)(p + 4);
  return r.v;
}

// ---------------------------------------------------------------------------
__global__ void transpose_w_kernel(const float* __restrict__ in, float* __restrict__ out,
                                   int NB, int OC, int IC, int K) {
  int total = NB * OC * IC * K;
  for (int i = blockIdx.x * blockDim.x + threadIdx.x; i < total; i += gridDim.x * blockDim.x) {
    int k  = i % K;
    int t  = i / K;
    int ic = t % IC; t /= IC;
    int oc = t % OC;
    int nb = t / OC;
    out[(((size_t)nb * IC + ic) * K + k) * OC + oc] = in[i];
  }
}

// ---------------------------------------------------------------------------
// Weight fragment prep: w[oc][ic][3][3] f32 -> MFMA B-frag order, bf16 hi/lo.
__global__ void prep_wfrag(const float* __restrict__ w, ushort_t* __restrict__ out,
                           int NGp, int ocreal, int wlstride, int olstride) {
  int layer = blockIdx.y;
  int elems = 9 * 2 * NGp * 64 * 8;
  int idx = blockIdx.x * 256 + threadIdx.x;
  if (idx >= elems) return;
  int j = idx & 7, lane = (idx >> 3) & 63;
  int rest = idx >> 9;
  int g = rest % NGp; rest /= NGp;
  int ih = rest & 1, tap = rest >> 1;
  int oc = g * 16 + (lane & 15);
  int ic = ih * 32 + (lane >> 4) * 8 + j;
  float v = 0.0f;
  if (oc < ocreal) v = w[(size_t)layer * wlstride + (oc * 64 + ic) * 9 + tap];
  uint32_t hi, lo;
  split_hl(v, hi, lo);
  out[(size_t)layer * olstride + idx] = (ushort_t)hi;
  out[(size_t)layer * olstride + elems + idx] = (ushort_t)lo;
}

// ---------------------------------------------------------------------------
__global__ void prep_kernel(const float* __restrict__ LowDEM, const float* __restrict__ Point_Ele,
                            const float* __restrict__ Slope, const float* __restrict__ Distance,
                            const float* __restrict__ Level, const float* __restrict__ w0,
                            const float* __restrict__ b0, float* __restrict__ x0) {
  int i = blockIdx.x * blockDim.x + threadIdx.x;
  if (i >= NPIX) return;
  float lv  = Level[i];
  float err = w0[0] * Slope[i] + w0[1] * Distance[i] + w0[2] * lv + b0[0];
  float lm  = (lv != 0.0f) ? 1.0f : 0.0f;
  x0[i] = LowDEM[i] * (1.0f - lm) + Point_Ele[i] + err * lm;
}

// ---------------------------------------------------------------------------
__global__ __launch_bounds__(256, 2)
void conv9x9_kernel(const float* __restrict__ in, const float* __restrict__ wT,
                    const float* __restrict__ bias, float* __restrict__ out) {
  const int tx = threadIdx.x & 15, ty = threadIdx.x >> 4;
  const int w0 = blockIdx.x * 16, h0 = blockIdx.y * 16, b = blockIdx.z;
  __shared__ float lds[24 * 24];
  for (int idx = threadIdx.x; idx < 576; idx += 256) {
    int yy = idx / 24, xx = idx - yy * 24;
    int gy = h0 + yy - 4, gx = w0 + xx - 4;
    float v = 0.0f;
    if ((unsigned)gy < 256u && (unsigned)gx < 256u) v = in[b * HW + gy * 256 + gx];
    lds[idx] = v;
  }
  __syncthreads();
  float acc[64];
#pragma unroll
  for (int o = 0; o < 64; o++) acc[o] = 0.0f;
#pragma unroll 1
  for (int i = 0; i < 9; i++) {
#pragma unroll
    for (int j = 0; j < 9; j++) {
      float v = lds[(ty + i) * 24 + tx + j];
      const float* wp = wT + (i * 9 + j) * 64;   // uniform -> s_load
#pragma unroll
      for (int o = 0; o < 64; o++) acc[o] = fmaf(v, wp[o], acc[o]);
    }
  }
  const int p = (h0 + ty) * 256 + (w0 + tx);
  float* op = out + (size_t)b * CHW + p;
#pragma unroll
  for (int o = 0; o < 64; o++) op[o * HW] = acc[o] + bias[o];
}

// ---------------------------------------------------------------------------
// MFMA conv3x3 (R11 form, kept): 16x4 tile, separated hi/lo planes, batched
// B-loads, unioned scratch, 31.9 KB LDS, __launch_bounds__(256,5).
// PLATEAU NOTE (R8-R11): conv dispatch time ~70us is invariant across B-load
// batching/pipelining, A-read width, MFMA:load intensity, and occupancy 3->5
// blocks/CU — limiter not reachable from this source structure.
// MODE 0 plain / 1 relu(bn) / 2 bn+skip (WRITEY: materialize y). INHWC:
// pixel-major input.
// ---------------------------------------------------------------------------
template <int NG, int MODE, int STATS, int OCLIM, int HASBIAS, int WRITEY, int INHWC>
__global__ __launch_bounds__(256, 5)
void mfma_conv3(const float* __restrict__ in, const float* __restrict__ skip,
                const ushort_t* __restrict__ wf,
                const float* __restrict__ bias, const float* __restrict__ stats_in,
                const float* __restrict__ gg, const float* __restrict__ be,
                float* __restrict__ stats_out, float* __restrict__ yout,
                float* __restrict__ out) {
  const int tid  = threadIdx.x;
  const int lane = tid & 63, wid = tid >> 6;
  const int m = lane & 15, quad = lane >> 4;
  const int x0 = blockIdx.x * 16, y0 = blockIdx.y * 4, b = blockIdx.z;
  constexpr int WT = 2 * NG * 64 * 8;          // ushorts per tap per plane
  __shared__ __align__(16) ushort_t xh[108 * 68];   // hi plane, [spat][ch]
  __shared__ __align__(16) ushort_t xl[108 * 68];   // lo plane
  __shared__ float s_sc[MODE ? 64 : 1], s_sh[MODE ? 64 : 1];
  __shared__ float scr[(MODE || STATS) ? 512 : 1];  // preamble slot-sums / stats reduce
  if (MODE) {
    int c = tid & 63, part = tid >> 6;
    float sum = 0.0f, sq = 0.0f;
    for (int sl = part; sl < NSLOT; sl += 4) {   // 4-way parallel slot sum
      sum += stats_in[sl * 128 + c];
      sq  += stats_in[sl * 128 + 64 + c];
    }
    scr[part * 64 + c] = sum;
    scr[256 + part * 64 + c] = sq;
    __syncthreads();
    if (tid < 64) {
      float s4 = scr[c] + scr[64 + c] + scr[128 + c] + scr[192 + c];
      float q4 = scr[256 + c] + scr[320 + c] + scr[384 + c] + scr[448 + c];
      float mn = s4 * INV_N, var = q4 * INV_N - mn * mn;
      float s = gg[c] * rsqrtf(var + EPSv);
      s_sc[c] = s;
      s_sh[c] = be[c] - mn * s;
    }
    __syncthreads();
  }
  const float* inb = in + (size_t)b * CHW;
  const float* skb = MODE == 2 ? skip + (size_t)b * CHW : nullptr;
  float* ytb = WRITEY ? yout + (size_t)b * CHW : nullptr;
  uint32_t* xh32 = (uint32_t*)xh;              // row stride 34 dwords
  uint32_t* xl32 = (uint32_t*)xl;
#pragma unroll
  for (int t = 0; t < 14; t++) {
    int idx = t * 256 + tid;                   // 3456 = 108 spat * 32 ic-pairs
    if (idx < 3456) {
      int r, icp;
      if (INHWC) { icp = idx & 31; r = idx >> 5; }   // tid-contig ic -> coalesced HWC
      else       { r = idx % 108; icp = idx / 108; } // tid-contig px -> coalesced NCHW
      int row = r / 18, col = r - row * 18;
      int gy = y0 - 1 + row, gx = x0 - 1 + col;
      float v0 = 0.0f, v1 = 0.0f;
      if ((unsigned)gy < 256u && (unsigned)gx < 256u) {
        int ic = icp * 2;
        if (INHWC) {
          float2 vv = *(const float2*)&inb[(size_t)(gy * 256 + gx) * 64 + ic];
          v0 = vv.x; v1 = vv.y;
        } else {
          v0 = inb[ic * HW + gy * 256 + gx];
          v1 = inb[(ic + 1) * HW + gy * 256 + gx];
        }
        if (MODE == 1) {
          v0 = fmaxf(fmaf(v0, s_sc[ic], s_sh[ic]), 0.0f);
          v1 = fmaxf(fmaf(v1, s_sc[ic + 1], s_sh[ic + 1]), 0.0f);
        }
        if (MODE == 2) {
          v0 = fmaf(v0, s_sc[ic], s_sh[ic]) + skb[ic * HW + gy * 256 + gx];
          v1 = fmaf(v1, s_sc[ic + 1], s_sh[ic + 1]) + skb[(ic + 1) * HW + gy * 256 + gx];
          if (WRITEY && row >= 1 && row <= 4 && col >= 1 && col <= 16) {
            ytb[ic * HW + gy * 256 + gx] = v0;
            ytb[(ic + 1) * HW + gy * 256 + gx] = v1;
          }
        }
      }
      uint32_t h0, l0, h1, l1;
      split_hl(v0, h0, l0);
      split_hl(v1, h1, l1);
      xh32[r * 34 + icp] = h0 | (h1 << 16);
      xl32[r * 34 + icp] = l0 | (l1 << 16);
    }
  }
  __syncthreads();                             // the ONLY barrier before epilogue
  f32x4 acc[NG];
#pragma unroll
  for (int g = 0; g < NG; g++) acc[g] = (f32x4){0.0f, 0.0f, 0.0f, 0.0f};

  const bf16x8* wfh = (const bf16x8*)wf;                 // hi plane, frag-ordered
  const bf16x8* wfl = (const bf16x8*)(wf + 9 * WT);      // lo plane

#pragma unroll 1
  for (int tap = 0; tap < 9; tap++) {
    bf16x8 bh[2][NG], bl[2][NG];
#pragma unroll
    for (int ih = 0; ih < 2; ih++)
#pragma unroll
      for (int g = 0; g < NG; g++) {
        int fi = ((tap * 2 + ih) * NG + g) * 64 + lane;
        bh[ih][g] = wfh[fi];
        bl[ih][g] = wfl[fi];
      }
    const int dy = tap / 3 - 1, dx = tap % 3 - 1;
    const int spat = (wid + dy + 1) * 18 + (m + dx + 1);
#pragma unroll
    for (int ih = 0; ih < 2; ih++) {
      const int base = spat * 68 + ih * 32 + quad * 8;
      bf16x8 ah = lds_ld16(xh + base);
      bf16x8 al = lds_ld16(xl + base);
#pragma unroll
      for (int g = 0; g < NG; g++) {
        acc[g] = __builtin_amdgcn_mfma_f32_16x16x32_bf16(ah, bh[ih][g], acc[g], 0, 0, 0);
        acc[g] = __builtin_amdgcn_mfma_f32_16x16x32_bf16(al, bh[ih][g], acc[g], 0, 0, 0);
        acc[g] = __builtin_amdgcn_mfma_f32_16x16x32_bf16(ah, bl[ih][g], acc[g], 0, 0, 0);
      }
    }
  }
  // epilogue: D[row=quad*4+r][col=lane&15] -> pixel (y0+wid, x0+quad*4+r), oc=g*16+m
  const int py = y0 + wid;
  float* ob = out + (size_t)b * OCLIM * HW + py * 256 + x0 + quad * 4;
#pragma unroll
  for (int g = 0; g < NG; g++) {
    int oc = g * 16 + m;
    if (oc < OCLIM) {
      float bv = HASBIAS ? bias[oc] : 0.0f;
#pragma unroll
      for (int r = 0; r < 4; r++) ob[oc * HW + r] = acc[g][r] + bv;
    }
    if (STATS) {
      float s  = acc[g][0] + acc[g][1] + acc[g][2] + acc[g][3];
      float s2 = acc[g][0] * acc[g][0] + acc[g][1] * acc[g][1] +
                 acc[g][2] * acc[g][2] + acc[g][3] * acc[g][3];
      s  += __shfl_xor(s, 16, 64);  s  += __shfl_xor(s, 32, 64);
      s2 += __shfl_xor(s2, 16, 64); s2 += __shfl_xor(s2, 32, 64);
      if (lane < 16) {
        scr[(0 * 4 + wid) * 64 + g * 16 + lane] = s;
        scr[(1 * 4 + wid) * 64 + g * 16 + lane] = s2;
      }
    }
  }
  if (STATS) {
    __syncthreads();
    if (tid < 128) {
      int oc = tid & 63, which = tid >> 6;
      float tot = scr[(which * 4 + 0) * 64 + oc] + scr[(which * 4 + 1) * 64 + oc] +
                  scr[(which * 4 + 2) * 64 + oc] + scr[(which * 4 + 3) * 64 + oc];
      int slot = (blockIdx.y * 16 + blockIdx.x) & (NSLOT - 1);
      atomicAdd(&stats_out[slot * 128 + which * 64 + oc], tot);
    }
  }
}

// ---------------------------------------------------------------------------
__global__ void bn_apply_add_kernel(const float* __restrict__ t, const float* __restrict__ stats,
                                    const float* __restrict__ g, const float* __restrict__ be,
                                    const float* __restrict__ skip, float* __restrict__ out) {
  __shared__ float s_sc[64], s_sh[64];
  if (threadIdx.x < 64) {
    int c = threadIdx.x;
    float sum = 0.0f, sq = 0.0f;
    for (int sl = 0; sl < NSLOT; sl++) {
      sum += stats[sl * 128 + c];
      sq  += stats[sl * 128 + 64 + c];
    }
    float m   = sum * INV_N;
    float var = sq * INV_N - m * m;
    float s   = g[c] * rsqrtf(var + EPSv);
    s_sc[c] = s;
    s_sh[c] = be[c] - m * s;
  }
  __syncthreads();
  const float4* t4 = (const float4*)t;
  const float4* k4 = (const float4*)skip;
  float4* o4 = (float4*)out;
  const int n4 = NCHW / 4;
  for (int i = blockIdx.x * blockDim.x + threadIdx.x; i < n4; i += gridDim.x * blockDim.x) {
    int c = (i >> 14) & 63;
    float s = s_sc[c], h = s_sh[c];
    float4 v = t4[i], kk = k4[i], r;
    r.x = fmaf(v.x, s, h) + kk.x;
    r.y = fmaf(v.y, s, h) + kk.y;
    r.z = fmaf(v.z, s, h) + kk.z;
    r.w = fmaf(v.w, s, h) + kk.w;
    o4[i] = r;
  }
}

// ---------------------------------------------------------------------------
// NCHW -> NHWC transpose (LDS-tiled, both sides coalesced, 64x65 pad).
// ---------------------------------------------------------------------------
__global__ __launch_bounds__(256, 4)
void nchw_to_nhwc(const float* __restrict__ in, float* __restrict__ out) {
  __shared__ float t[64][65];
  const int blk = blockIdx.x;            // 2048 = NPIX/64
  const int b = blk >> 10;
  const int p0 = (blk & 1023) * 64;
  const float* ib = in + (size_t)b * CHW;
  float* ob = out + (size_t)b * CHW;
#pragma unroll
  for (int i = 0; i < 16; i++) {
    int idx = i * 256 + threadIdx.x;
    int c = idx >> 6, p = idx & 63;
    t[c][p] = ib[c * HW + p0 + p];
  }
  __syncthreads();
#pragma unroll
  for (int i = 0; i < 16; i++) {
    int idx = i * 256 + threadIdx.x;
    int p = idx >> 6, c = idx & 63;
    ob[(size_t)(p0 + p) * 64 + c] = t[c][p];
  }
}

// ---------------------------------------------------------------------------
// Deformable conv on MFMA, HWC input (R9 form): separated hi/lo planes, 128B
// rows + 32B-chunk XOR swizzle, double-buffered, 1 barrier/tap.
// R12: __launch_bounds__ REVERTED to (256,4). R11's (256,5) tightened the
// VGPR cap -> compiler spilled the K-loop working set to scratch (VGPR 60->48,
// FETCH 36->377 MB, WRITE 33->466 MB, 165->258 us). Known-good: VGPR 60,
// 4 blocks/CU, 41% occupancy, no spill.
// FINAL: OC=1, fuse dc4 bias + conv4, write d_out planar.
// ---------------------------------------------------------------------------
template <int NG, int FINAL>
__global__ __launch_bounds__(256, 4)
void dcn_mfma(const float* __restrict__ xhwc, const float* __restrict__ om,
              const ushort_t* __restrict__ wf, const float* __restrict__ bias,
              const float* __restrict__ c4w, const float* __restrict__ c4b,
              float* __restrict__ out) {
  const int tid  = threadIdx.x;
  const int lane = tid & 63, wid = tid >> 6;
  const int m = lane & 15, quad = lane >> 4;
  const int x0 = blockIdx.x * 16, y0 = blockIdx.y * 4, b = blockIdx.z;
  constexpr int WT = 2 * NG * 64 * 8;
  __shared__ __align__(16) ushort_t sh[2][64 * 64];   // hi plane per buffer, 8 KB
  __shared__ __align__(16) ushort_t sl[2][64 * 64];   // lo plane
  const int gpx = tid & 63, cg = tid >> 6;     // gather role: pixel, 16-ch group
  const int gpy = y0 + (gpx >> 4), gxx = x0 + (gpx & 15);
  const float* xb  = xhwc + (size_t)b * CHW;
  const float* omb = om + (size_t)b * 27 * HW + gpy * 256 + gxx;
  const int wchunk = (cg ^ (gpx & 3)) * 16;    // swizzled 32B-chunk base (ushorts)

  auto gather = [&](int tap, int buf) {
    float dyv = omb[tap * HW];
    float dxv = omb[(9 + tap) * HW];
    float mo  = omb[(18 + tap) * HW];
    float mk  = 1.0f / (1.0f + __expf(-mo));
    float ys = fminf(fmaxf((float)(gpy + tap / 3 - 1) + dyv, -2.0f), 258.0f);
    float xs = fminf(fmaxf((float)(gxx + tap % 3 - 1) + dxv, -2.0f), 258.0f);
    float y0f = floorf(ys), x0f = floorf(xs);
    float wy = ys - y0f, wx = xs - x0f;
    int yi = (int)y0f, xi = (int)x0f;
    float vy0 = ((unsigned)yi       < 256u) ? 1.0f : 0.0f;
    float vy1 = ((unsigned)(yi + 1) < 256u) ? 1.0f : 0.0f;
    float vx0 = ((unsigned)xi       < 256u) ? 1.0f : 0.0f;
    float vx1 = ((unsigned)(xi + 1) < 256u) ? 1.0f : 0.0f;
    int cy0 = min(max(yi, 0), 255), cy1 = min(max(yi + 1, 0), 255);
    int cx0 = min(max(xi, 0), 255), cx1 = min(max(xi + 1, 0), 255);
    float W00 = (1.0f - wy) * (1.0f - wx) * mk * vy0 * vx0;
    float W01 = (1.0f - wy) * wx * mk * vy0 * vx1;
    float W10 = wy * (1.0f - wx) * mk * vy1 * vx0;
    float W11 = wy * wx * mk * vy1 * vx1;
    const float* p00 = xb + (size_t)(cy0 * 256 + cx0) * 64 + cg * 16;
    const float* p01 = xb + (size_t)(cy0 * 256 + cx1) * 64 + cg * 16;
    const float* p10 = xb + (size_t)(cy1 * 256 + cx0) * 64 + cg * 16;
    const float* p11 = xb + (size_t)(cy1 * 256 + cx1) * 64 + cg * 16;
#pragma unroll
    for (int q4 = 0; q4 < 4; q4++) {
      float4 a  = ((const float4*)p00)[q4];
      float4 b2 = ((const float4*)p01)[q4];
      float4 c2 = ((const float4*)p10)[q4];
      float4 d2 = ((const float4*)p11)[q4];
      float s0 = W00 * a.x + W01 * b2.x + W10 * c2.x + W11 * d2.x;
      float s1 = W00 * a.y + W01 * b2.y + W10 * c2.y + W11 * d2.y;
      float s2 = W00 * a.z + W01 * b2.z + W10 * c2.z + W11 * d2.z;
      float s3 = W00 * a.w + W01 * b2.w + W10 * c2.w + W11 * d2.w;
      uint32_t h0, l0, h1, l1, h2, l2, h3, l3;
      split_hl(s0, h0, l0); split_hl(s1, h1, l1);
      split_hl(s2, h2, l2); split_hl(s3, h3, l3);
      int wi = gpx * 64 + wchunk + q4 * 4;     // 8B-aligned
      *(uint2*)&sh[buf][wi] = make_uint2(h0 | (h1 << 16), h2 | (h3 << 16));
      *(uint2*)&sl[buf][wi] = make_uint2(l0 | (l1 << 16), l2 | (l3 << 16));
    }
  };

  f32x4 acc[NG];
#pragma unroll
  for (int g = 0; g < NG; g++) acc[g] = (f32x4){0.0f, 0.0f, 0.0f, 0.0f};
  const bf16x8* wfh = (const bf16x8*)wf;
  const bf16x8* wfl = (const bf16x8*)(wf + 9 * WT);
  const int px = wid * 16 + m;                 // this lane's A-row pixel

  gather(0, 0);
  __syncthreads();
#pragma unroll 1
  for (int tap = 0; tap < 9; tap++) {
    const int cur = tap & 1;
    if (tap < 8) gather(tap + 1, cur ^ 1);     // overlaps MFMAs below
#pragma unroll
    for (int ih = 0; ih < 2; ih++) {
      const int c = ih * 2 + (quad >> 1), h = quad & 1;
      const int ri = px * 64 + ((c ^ (px & 3)) * 16) + h * 8;   // 16B-aligned
      bf16x8 ah = *(const bf16x8*)&sh[cur][ri];
      bf16x8 al = *(const bf16x8*)&sl[cur][ri];
#pragma unroll
      for (int g = 0; g < NG; g++) {
        int fi = ((tap * 2 + ih) * NG + g) * 64 + lane;
        bf16x8 bh = wfh[fi], bl = wfl[fi];
        acc[g] = __builtin_amdgcn_mfma_f32_16x16x32_bf16(ah, bh, acc[g], 0, 0, 0);
        acc[g] = __builtin_amdgcn_mfma_f32_16x16x32_bf16(al, bh, acc[g], 0, 0, 0);
        acc[g] = __builtin_amdgcn_mfma_f32_16x16x32_bf16(ah, bl, acc[g], 0, 0, 0);
      }
    }
    __syncthreads();   // writes to buf^1 and reads of cur both done
  }
  const int py = y0 + wid;
  if (FINAL) {
    if (m == 0) {
      float* op = out + (size_t)b * HW + py * 256 + x0 + quad * 4;
#pragma unroll
      for (int r = 0; r < 4; r++) op[r] = c4w[0] * (acc[0][r] + bias[0]) + c4b[0];
    }
  } else {
    float* ob = out + (size_t)b * CHW + ((size_t)py * 256 + x0 + quad * 4) * 64 + m;
#pragma unroll
    for (int g = 0; g < NG; g++)
#pragma unroll
      for (int r = 0; r < 4; r++)
        ob[r * 64 + g * 16] = fmaxf(acc[g][r] + bias[g * 16 + m], 0.0f);
  }
}

// ---------------------------------------------------------------------------
extern "C" void kernel_launch(void* const* d_in, const int* in_sizes, int n_in,
                              void* d_out, int out_size, void* d_ws, size_t ws_size,
                              hipStream_t stream) {
  const float* LowDEM    = (const float*)d_in[0];
  const float* Point_Ele = (const float*)d_in[1];
  const float* Slope     = (const float*)d_in[2];
  const float* Distance  = (const float*)d_in[3];
  const float* Level     = (const float*)d_in[4];
  const float* conv0_w   = (const float*)d_in[5];
  const float* conv0_b   = (const float*)d_in[6];
  const float* conv1_w   = (const float*)d_in[7];
  const float* conv1_b   = (const float*)d_in[8];
  const float* rb_w1     = (const float*)d_in[9];
  const float* rb_g1     = (const float*)d_in[11];
  const float* rb_be1    = (const float*)d_in[12];
  const float* rb_w2     = (const float*)d_in[13];
  const float* rb_g2     = (const float*)d_in[15];
  const float* rb_be2    = (const float*)d_in[16];
  const float* conv2_w   = (const float*)d_in[17];
  const float* bn2_g     = (const float*)d_in[19];
  const float* bn2_be    = (const float*)d_in[20];
  const float* dc2_w     = (const float*)d_in[21];
  const float* dc2_b     = (const float*)d_in[22];
  const float* dc2_ow    = (const float*)d_in[23];
  const float* dc2_ob    = (const float*)d_in[24];
  const float* dc3_w     = (const float*)d_in[25];
  const float* dc3_b     = (const float*)d_in[26];
  const float* dc3_ow    = (const float*)d_in[27];
  const float* dc3_ob    = (const float*)d_in[28];
  const float* dc4_w     = (const float*)d_in[29];
  const float* dc4_b     = (const float*)d_in[30];
  const float* dc4_ow    = (const float*)d_in[31];
  const float* dc4_ob    = (const float*)d_in[32];
  const float* conv4_w   = (const float*)d_in[33];
  const float* conv4_b   = (const float*)d_in[34];

  // small region first, then big buffers
  float* x0   = (float*)d_ws;             // 131072
  float* T1   = x0 + NPIX;                // 5184
  ushort_t* WF = (ushort_t*)(T1 + 5184);  // 39 * WFL ushorts
  float* stats = (float*)(WF + 39 * WFL); // 33 * STSLOT floats
  float* big   = stats + 33 * STSLOT;
  size_t used_small = (size_t)((char*)big - (char*)d_ws);
  bool fused = ws_size >= used_small + 5ull * NCHW * sizeof(float);

  float* bufX  = big;                     // X (conv9x9 out; skip for bn2)
  float* bufT  = bufX + NCHW;             // t1 / conv2 out / offset-conv out
  float* bufT2 = bufT + NCHW;             // t2
  float* yA    = bufT2 + NCHW;            // y ping
  float* yB    = fused ? yA + NCHW : yA;  // y pong (legacy: aliases yA)

  hipMemsetAsync(stats, 0, 33 * STSLOT * sizeof(float), stream);

  transpose_w_kernel<<<32, 256, 0, stream>>>(conv1_w, T1, 1, 64, 1, 81);

  prep_wfrag<<<dim3(144, 16), 256, 0, stream>>>(rb_w1,   WF,            4, 64, 36864, WFL);
  prep_wfrag<<<dim3(144, 16), 256, 0, stream>>>(rb_w2,   WF + 16 * WFL, 4, 64, 36864, WFL);
  prep_wfrag<<<dim3(144, 1),  256, 0, stream>>>(conv2_w, WF + 32 * WFL, 4, 64, 36864, WFL);
  prep_wfrag<<<dim3(72, 1),   256, 0, stream>>>(dc2_ow,  WF + 33 * WFL, 2, 27, 15552, WFL);
  prep_wfrag<<<dim3(72, 1),   256, 0, stream>>>(dc3_ow,  WF + 34 * WFL, 2, 27, 15552, WFL);
  prep_wfrag<<<dim3(72, 1),   256, 0, stream>>>(dc4_ow,  WF + 35 * WFL, 2, 27, 15552, WFL);
  prep_wfrag<<<dim3(144, 1),  256, 0, stream>>>(dc2_w,   WF + 36 * WFL, 4, 64, 36864, WFL);
  prep_wfrag<<<dim3(144, 1),  256, 0, stream>>>(dc3_w,   WF + 37 * WFL, 4, 64, 36864, WFL);
  prep_wfrag<<<dim3(36, 1),   256, 0, stream>>>(dc4_w,   WF + 38 * WFL, 1, 1, 576, WFL);

  prep_kernel<<<(NPIX + 255) / 256, 256, 0, stream>>>(LowDEM, Point_Ele, Slope, Distance,
                                                      Level, conv0_w, conv0_b, x0);

  dim3 grid16(16, 16, 2);   // conv9x9
  dim3 gmf(16, 64, 2);      // mfma conv3x3 / dcn_mfma (16x4 pixel tiles)

  conv9x9_kernel<<<grid16, 256, 0, stream>>>(x0, T1, conv1_b, bufX);   // X in bufX

  if (fused) {
    mfma_conv3<4, 0, 1, 64, 0, 0, 0><<<gmf, 256, 0, stream>>>(
        bufX, nullptr, WF, nullptr, nullptr, nullptr, nullptr,
        stats, nullptr, bufT);
    mfma_conv3<4, 1, 1, 64, 0, 0, 0><<<gmf, 256, 0, stream>>>(
        bufT, nullptr, WF + 16 * WFL, nullptr, stats,
        rb_g1, rb_be1, stats + STSLOT, nullptr, bufT2);
    for (int i = 1; i < 16; i++) {
      const float* skp = (i == 1) ? bufX : ((i & 1) ? yB : yA);  // y_{i-2}
      float* yo = (i & 1) ? yA : yB;                              // y_{i-1}
      mfma_conv3<4, 2, 1, 64, 0, 1, 0><<<gmf, 256, 0, stream>>>(
          bufT2, skp, WF + (size_t)i * WFL, nullptr, stats + (2 * i - 1) * STSLOT,
          rb_g2 + (i - 1) * 64, rb_be2 + (i - 1) * 64,
          stats + (2 * i) * STSLOT, yo, bufT);
      mfma_conv3<4, 1, 1, 64, 0, 0, 0><<<gmf, 256, 0, stream>>>(
          bufT, nullptr, WF + (size_t)(16 + i) * WFL, nullptr, stats + (2 * i) * STSLOT,
          rb_g1 + i * 64, rb_be1 + i * 64, stats + (2 * i + 1) * STSLOT, nullptr, bufT2);
    }
    mfma_conv3<4, 2, 1, 64, 0, 0, 0><<<gmf, 256, 0, stream>>>(
        bufT2, yA, WF + (size_t)32 * WFL, nullptr, stats + 31 * STSLOT,
        rb_g2 + 15 * 64, rb_be2 + 15 * 64, stats + 32 * STSLOT, nullptr, bufT);
  } else {
    float* bufY = yA;
    for (int i = 0; i < 16; i++) {
      const float* src = (i == 0) ? bufX : bufY;
      mfma_conv3<4, 0, 1, 64, 0, 0, 0><<<gmf, 256, 0, stream>>>(
          src, nullptr, WF + (size_t)i * WFL, nullptr, nullptr, nullptr, nullptr,
          stats + (2 * i) * STSLOT, nullptr, bufT);
      mfma_conv3<4, 1, 1, 64, 0, 0, 0><<<gmf, 256, 0, stream>>>(
          bufT, nullptr, WF + (size_t)(16 + i) * WFL, nullptr, stats + (2 * i) * STSLOT,
          rb_g1 + i * 64, rb_be1 + i * 64, stats + (2 * i + 1) * STSLOT, nullptr, bufT2);
      bn_apply_add_kernel<<<2048, 256, 0, stream>>>(bufT2, stats + (2 * i + 1) * STSLOT,
                                                    rb_g2 + i * 64, rb_be2 + i * 64, src, bufY);
    }
    mfma_conv3<4, 0, 1, 64, 0, 0, 0><<<gmf, 256, 0, stream>>>(
        bufY, nullptr, WF + (size_t)32 * WFL, nullptr, nullptr, nullptr, nullptr,
        stats + 32 * STSLOT, nullptr, bufT);
  }

  // x = bn(conv2_out) + X  -> bufX (planar)
  bn_apply_add_kernel<<<2048, 256, 0, stream>>>(bufT, stats + 32 * STSLOT, bn2_g, bn2_be,
                                                bufX, bufX);

  // HWC mirror of x for the dcn gather
  float* xT    = fused ? yB : yA;     // free by now
  float* d2out = fused ? yA : bufT2;  // dc2 output (HWC)
  float* d3out = fused ? bufT2 : yA;  // dc3 output (HWC)
  nchw_to_nhwc<<<2048, 256, 0, stream>>>(bufX, xT);

  // dc2
  mfma_conv3<2, 0, 0, 27, 1, 0, 0><<<gmf, 256, 0, stream>>>(
      bufX, nullptr, WF + (size_t)33 * WFL, dc2_ob, nullptr, nullptr, nullptr,
      nullptr, nullptr, bufT);
  dcn_mfma<4, 0><<<gmf, 256, 0, stream>>>(xT, bufT, WF + (size_t)36 * WFL, dc2_b,
                                          nullptr, nullptr, d2out);
  // dc3
  mfma_conv3<2, 0, 0, 27, 1, 0, 1><<<gmf, 256, 0, stream>>>(
      d2out, nullptr, WF + (size_t)34 * WFL, dc3_ob, nullptr, nullptr, nullptr,
      nullptr, nullptr, bufT);
  dcn_mfma<4, 0><<<gmf, 256, 0, stream>>>(d2out, bufT, WF + (size_t)37 * WFL, dc3_b,
                                          nullptr, nullptr, d3out);
  // dc4 + conv4 -> d_out
  mfma_conv3<2, 0, 0, 27, 1, 0, 1><<<gmf, 256, 0, stream>>>(
      d3out, nullptr, WF + (size_t)35 * WFL, dc4_ob, nullptr, nullptr, nullptr,
      nullptr, nullptr, bufT);
  dcn_mfma<1, 1><<<gmf, 256, 0, stream>>>(d3out, bufT, WF + (size_t)38 * WFL, dc4_b,
                                          conv4_w, conv4_b, (float*)d_out);
}

// Round 13
// 3258.646 us; speedup vs baseline: 1.0638x; 1.0062x over previous
//
#include <hip/hip_runtime.h>
#include <cmath>

typedef unsigned short ushort_t;
typedef __attribute__((ext_vector_type(8))) short bf16x8;
typedef __attribute__((ext_vector_type(4))) float f32x4;

// Problem constants (B=2, C=64, H=W=256)
static constexpr int Bn   = 2;
static constexpr int Hn   = 256;
static constexpr int Wn   = 256;
static constexpr int HW   = Hn * Wn;          // 65536
static constexpr int CHW  = 64 * HW;          // 4194304
static constexpr int NCHW = Bn * CHW;         // 8388608
static constexpr int NPIX = Bn * HW;          // 131072
static constexpr float EPSv = 1e-5f;
static constexpr float INV_N = 1.0f / 131072.0f;   // BN count = B*H*W
static constexpr int NSLOT = 64;              // stats slot replication (anti-contention)
static constexpr int STSLOT = NSLOT * 128;    // floats per layer stats region
static constexpr int WFL = 73728;             // ushorts per weight-fragment layer slot

// bf16 round-to-nearest-even (no NaN inputs in this net)
__device__ inline uint32_t bf16_rne(float f) {
  uint32_t u = __float_as_uint(f);
  return (u + 0x7FFFu + ((u >> 16) & 1u)) >> 16;
}
__device__ inline void split_hl(float v, uint32_t& h, uint32_t& l) {
  h = bf16_rne(v);
  l = bf16_rne(v - __uint_as_float(h << 16)) & 0xFFFFu;
}
__device__ inline bf16x8 lds_ld16(const ushort_t* p) {   // 2x ds_read_b64
  union { bf16x8 v; uint2 u[2]; } r;
  r.u[0] = *(const uint2*)p;
  r.u[1] = *(const uint2*)(p + 4);
  return r.v;
}

// ---------------------------------------------------------------------------
__global__ void transpose_w_kernel(const float* __restrict__ in, float* __restrict__ out,
                                   int NB, int OC, int IC, int K) {
  int total = NB * OC * IC * K;
  for (int i = blockIdx.x * blockDim.x + threadIdx.x; i < total; i += gridDim.x * blockDim.x) {
    int k  = i % K;
    int t  = i / K;
    int ic = t % IC; t /= IC;
    int oc = t % OC;
    int nb = t / OC;
    out[(((size_t)nb * IC + ic) * K + k) * OC + oc] = in[i];
  }
}

// ---------------------------------------------------------------------------
// Weight fragment prep: w[oc][ic][3][3] f32 -> MFMA B-frag order, bf16 hi/lo.
__global__ void prep_wfrag(const float* __restrict__ w, ushort_t* __restrict__ out,
                           int NGp, int ocreal, int wlstride, int olstride) {
  int layer = blockIdx.y;
  int elems = 9 * 2 * NGp * 64 * 8;
  int idx = blockIdx.x * 256 + threadIdx.x;
  if (idx >= elems) return;
  int j = idx & 7, lane = (idx >> 3) & 63;
  int rest = idx >> 9;
  int g = rest % NGp; rest /= NGp;
  int ih = rest & 1, tap = rest >> 1;
  int oc = g * 16 + (lane & 15);
  int ic = ih * 32 + (lane >> 4) * 8 + j;
  float v = 0.0f;
  if (oc < ocreal) v = w[(size_t)layer * wlstride + (oc * 64 + ic) * 9 + tap];
  uint32_t hi, lo;
  split_hl(v, hi, lo);
  out[(size_t)layer * olstride + idx] = (ushort_t)hi;
  out[(size_t)layer * olstride + elems + idx] = (ushort_t)lo;
}

// ---------------------------------------------------------------------------
__global__ void prep_kernel(const float* __restrict__ LowDEM, const float* __restrict__ Point_Ele,
                            const float* __restrict__ Slope, const float* __restrict__ Distance,
                            const float* __restrict__ Level, const float* __restrict__ w0,
                            const float* __restrict__ b0, float* __restrict__ x0) {
  int i = blockIdx.x * blockDim.x + threadIdx.x;
  if (i >= NPIX) return;
  float lv  = Level[i];
  float err = w0[0] * Slope[i] + w0[1] * Distance[i] + w0[2] * lv + b0[0];
  float lm  = (lv != 0.0f) ? 1.0f : 0.0f;
  x0[i] = LowDEM[i] * (1.0f - lm) + Point_Ele[i] + err * lm;
}

// ---------------------------------------------------------------------------
__global__ __launch_bounds__(256, 2)
void conv9x9_kernel(const float* __restrict__ in, const float* __restrict__ wT,
                    const float* __restrict__ bias, float* __restrict__ out) {
  const int tx = threadIdx.x & 15, ty = threadIdx.x >> 4;
  const int w0 = blockIdx.x * 16, h0 = blockIdx.y * 16, b = blockIdx.z;
  __shared__ float lds[24 * 24];
  for (int idx = threadIdx.x; idx < 576; idx += 256) {
    int yy = idx / 24, xx = idx - yy * 24;
    int gy = h0 + yy - 4, gx = w0 + xx - 4;
    float v = 0.0f;
    if ((unsigned)gy < 256u && (unsigned)gx < 256u) v = in[b * HW + gy * 256 + gx];
    lds[idx] = v;
  }
  __syncthreads();
  float acc[64];
#pragma unroll
  for (int o = 0; o < 64; o++) acc[o] = 0.0f;
#pragma unroll 1
  for (int i = 0; i < 9; i++) {
#pragma unroll
    for (int j = 0; j < 9; j++) {
      float v = lds[(ty + i) * 24 + tx + j];
      const float* wp = wT + (i * 9 + j) * 64;   // uniform -> s_load
#pragma unroll
      for (int o = 0; o < 64; o++) acc[o] = fmaf(v, wp[o], acc[o]);
    }
  }
  const int p = (h0 + ty) * 256 + (w0 + tx);
  float* op = out + (size_t)b * CHW + p;
#pragma unroll
  for (int o = 0; o < 64; o++) op[o * HW] = acc[o] + bias[o];
}

// ---------------------------------------------------------------------------
// MFMA conv3x3 — R13: bounds back to (256,3), the R9 measured-best point.
// ERRATA on R11's theory: launch_bounds' 2nd arg is a register-allocator
// MINIMUM, not a residency cap — 31.5 KB LDS already allowed 5 blocks/CU at
// bounds 3; bounds 5 only tightened VGPR caps (neutral-to-negative here,
// spill-catastrophic for dcn in R11).
// PLATEAU (R8-R12, 5 experiments): ~65-70 us/dispatch invariant across
// B-load batching/pipelining, A-read width, MFMA:load intensity, occupancy
// bounds. Estimated VALU+staging floor ~35-45 us; residual is staging-latency
// + barrier tail, unreachable from this 2-phase structure.
// MODE 0 plain / 1 relu(bn) / 2 bn+skip (WRITEY: materialize y). INHWC:
// pixel-major input.
// ---------------------------------------------------------------------------
template <int NG, int MODE, int STATS, int OCLIM, int HASBIAS, int WRITEY, int INHWC>
__global__ __launch_bounds__(256, 3)
void mfma_conv3(const float* __restrict__ in, const float* __restrict__ skip,
                const ushort_t* __restrict__ wf,
                const float* __restrict__ bias, const float* __restrict__ stats_in,
                const float* __restrict__ gg, const float* __restrict__ be,
                float* __restrict__ stats_out, float* __restrict__ yout,
                float* __restrict__ out) {
  const int tid  = threadIdx.x;
  const int lane = tid & 63, wid = tid >> 6;
  const int m = lane & 15, quad = lane >> 4;
  const int x0 = blockIdx.x * 16, y0 = blockIdx.y * 4, b = blockIdx.z;
  constexpr int WT = 2 * NG * 64 * 8;          // ushorts per tap per plane
  __shared__ __align__(16) ushort_t xh[108 * 68];   // hi plane, [spat][ch]
  __shared__ __align__(16) ushort_t xl[108 * 68];   // lo plane
  __shared__ float s_sc[MODE ? 64 : 1], s_sh[MODE ? 64 : 1];
  __shared__ float scr[(MODE || STATS) ? 512 : 1];  // preamble slot-sums / stats reduce
  if (MODE) {
    int c = tid & 63, part = tid >> 6;
    float sum = 0.0f, sq = 0.0f;
    for (int sl = part; sl < NSLOT; sl += 4) {   // 4-way parallel slot sum
      sum += stats_in[sl * 128 + c];
      sq  += stats_in[sl * 128 + 64 + c];
    }
    scr[part * 64 + c] = sum;
    scr[256 + part * 64 + c] = sq;
    __syncthreads();
    if (tid < 64) {
      float s4 = scr[c] + scr[64 + c] + scr[128 + c] + scr[192 + c];
      float q4 = scr[256 + c] + scr[320 + c] + scr[384 + c] + scr[448 + c];
      float mn = s4 * INV_N, var = q4 * INV_N - mn * mn;
      float s = gg[c] * rsqrtf(var + EPSv);
      s_sc[c] = s;
      s_sh[c] = be[c] - mn * s;
    }
    __syncthreads();
  }
  const float* inb = in + (size_t)b * CHW;
  const float* skb = MODE == 2 ? skip + (size_t)b * CHW : nullptr;
  float* ytb = WRITEY ? yout + (size_t)b * CHW : nullptr;
  uint32_t* xh32 = (uint32_t*)xh;              // row stride 34 dwords
  uint32_t* xl32 = (uint32_t*)xl;
#pragma unroll
  for (int t = 0; t < 14; t++) {
    int idx = t * 256 + tid;                   // 3456 = 108 spat * 32 ic-pairs
    if (idx < 3456) {
      int r, icp;
      if (INHWC) { icp = idx & 31; r = idx >> 5; }   // tid-contig ic -> coalesced HWC
      else       { r = idx % 108; icp = idx / 108; } // tid-contig px -> coalesced NCHW
      int row = r / 18, col = r - row * 18;
      int gy = y0 - 1 + row, gx = x0 - 1 + col;
      float v0 = 0.0f, v1 = 0.0f;
      if ((unsigned)gy < 256u && (unsigned)gx < 256u) {
        int ic = icp * 2;
        if (INHWC) {
          float2 vv = *(const float2*)&inb[(size_t)(gy * 256 + gx) * 64 + ic];
          v0 = vv.x; v1 = vv.y;
        } else {
          v0 = inb[ic * HW + gy * 256 + gx];
          v1 = inb[(ic + 1) * HW + gy * 256 + gx];
        }
        if (MODE == 1) {
          v0 = fmaxf(fmaf(v0, s_sc[ic], s_sh[ic]), 0.0f);
          v1 = fmaxf(fmaf(v1, s_sc[ic + 1], s_sh[ic + 1]), 0.0f);
        }
        if (MODE == 2) {
          v0 = fmaf(v0, s_sc[ic], s_sh[ic]) + skb[ic * HW + gy * 256 + gx];
          v1 = fmaf(v1, s_sc[ic + 1], s_sh[ic + 1]) + skb[(ic + 1) * HW + gy * 256 + gx];
          if (WRITEY && row >= 1 && row <= 4 && col >= 1 && col <= 16) {
            ytb[ic * HW + gy * 256 + gx] = v0;
            ytb[(ic + 1) * HW + gy * 256 + gx] = v1;
          }
        }
      }
      uint32_t h0, l0, h1, l1;
      split_hl(v0, h0, l0);
      split_hl(v1, h1, l1);
      xh32[r * 34 + icp] = h0 | (h1 << 16);
      xl32[r * 34 + icp] = l0 | (l1 << 16);
    }
  }
  __syncthreads();                             // the ONLY barrier before epilogue
  f32x4 acc[NG];
#pragma unroll
  for (int g = 0; g < NG; g++) acc[g] = (f32x4){0.0f, 0.0f, 0.0f, 0.0f};

  const bf16x8* wfh = (const bf16x8*)wf;                 // hi plane, frag-ordered
  const bf16x8* wfl = (const bf16x8*)(wf + 9 * WT);      // lo plane

#pragma unroll 1
  for (int tap = 0; tap < 9; tap++) {
    bf16x8 bh[2][NG], bl[2][NG];
#pragma unroll
    for (int ih = 0; ih < 2; ih++)
#pragma unroll
      for (int g = 0; g < NG; g++) {
        int fi = ((tap * 2 + ih) * NG + g) * 64 + lane;
        bh[ih][g] = wfh[fi];
        bl[ih][g] = wfl[fi];
      }
    const int dy = tap / 3 - 1, dx = tap % 3 - 1;
    const int spat = (wid + dy + 1) * 18 + (m + dx + 1);
#pragma unroll
    for (int ih = 0; ih < 2; ih++) {
      const int base = spat * 68 + ih * 32 + quad * 8;
      bf16x8 ah = lds_ld16(xh + base);
      bf16x8 al = lds_ld16(xl + base);
#pragma unroll
      for (int g = 0; g < NG; g++) {
        acc[g] = __builtin_amdgcn_mfma_f32_16x16x32_bf16(ah, bh[ih][g], acc[g], 0, 0, 0);
        acc[g] = __builtin_amdgcn_mfma_f32_16x16x32_bf16(al, bh[ih][g], acc[g], 0, 0, 0);
        acc[g] = __builtin_amdgcn_mfma_f32_16x16x32_bf16(ah, bl[ih][g], acc[g], 0, 0, 0);
      }
    }
  }
  // epilogue: D[row=quad*4+r][col=lane&15] -> pixel (y0+wid, x0+quad*4+r), oc=g*16+m
  const int py = y0 + wid;
  float* ob = out + (size_t)b * OCLIM * HW + py * 256 + x0 + quad * 4;
#pragma unroll
  for (int g = 0; g < NG; g++) {
    int oc = g * 16 + m;
    if (oc < OCLIM) {
      float bv = HASBIAS ? bias[oc] : 0.0f;
#pragma unroll
      for (int r = 0; r < 4; r++) ob[oc * HW + r] = acc[g][r] + bv;
    }
    if (STATS) {
      float s  = acc[g][0] + acc[g][1] + acc[g][2] + acc[g][3];
      float s2 = acc[g][0] * acc[g][0] + acc[g][1] * acc[g][1] +
                 acc[g][2] * acc[g][2] + acc[g][3] * acc[g][3];
      s  += __shfl_xor(s, 16, 64);  s  += __shfl_xor(s, 32, 64);
      s2 += __shfl_xor(s2, 16, 64); s2 += __shfl_xor(s2, 32, 64);
      if (lane < 16) {
        scr[(0 * 4 + wid) * 64 + g * 16 + lane] = s;
        scr[(1 * 4 + wid) * 64 + g * 16 + lane] = s2;
      }
    }
  }
  if (STATS) {
    __syncthreads();
    if (tid < 128) {
      int oc = tid & 63, which = tid >> 6;
      float tot = scr[(which * 4 + 0) * 64 + oc] + scr[(which * 4 + 1) * 64 + oc] +
                  scr[(which * 4 + 2) * 64 + oc] + scr[(which * 4 + 3) * 64 + oc];
      int slot = (blockIdx.y * 16 + blockIdx.x) & (NSLOT - 1);
      atomicAdd(&stats_out[slot * 128 + which * 64 + oc], tot);
    }
  }
}

// ---------------------------------------------------------------------------
// Legacy path only: y = BN(t)*g+be + skip (float4).
// ---------------------------------------------------------------------------
__global__ void bn_apply_add_kernel(const float* __restrict__ t, const float* __restrict__ stats,
                                    const float* __restrict__ g, const float* __restrict__ be,
                                    const float* __restrict__ skip, float* __restrict__ out) {
  __shared__ float s_sc[64], s_sh[64];
  if (threadIdx.x < 64) {
    int c = threadIdx.x;
    float sum = 0.0f, sq = 0.0f;
    for (int sl = 0; sl < NSLOT; sl++) {
      sum += stats[sl * 128 + c];
      sq  += stats[sl * 128 + 64 + c];
    }
    float m   = sum * INV_N;
    float var = sq * INV_N - m * m;
    float s   = g[c] * rsqrtf(var + EPSv);
    s_sc[c] = s;
    s_sh[c] = be[c] - m * s;
  }
  __syncthreads();
  const float4* t4 = (const float4*)t;
  const float4* k4 = (const float4*)skip;
  float4* o4 = (float4*)out;
  const int n4 = NCHW / 4;
  for (int i = blockIdx.x * blockDim.x + threadIdx.x; i < n4; i += gridDim.x * blockDim.x) {
    int c = (i >> 14) & 63;
    float s = s_sc[c], h = s_sh[c];
    float4 v = t4[i], kk = k4[i], r;
    r.x = fmaf(v.x, s, h) + kk.x;
    r.y = fmaf(v.y, s, h) + kk.y;
    r.z = fmaf(v.z, s, h) + kk.z;
    r.w = fmaf(v.w, s, h) + kk.w;
    o4[i] = r;
  }
}

// ---------------------------------------------------------------------------
// R13: fused x = bn(t)+skip -> planar out AND HWC mirror in one LDS-tiled
// pass (merges the old bn_apply_add + nchw_to_nhwc: saves one 33 MB re-read
// + a launch). Block = 64 ch x 64 px tile, both global sides coalesced.
// ---------------------------------------------------------------------------
__global__ __launch_bounds__(256, 4)
void bn_tx_kernel(const float* __restrict__ t, const float* __restrict__ stats,
                  const float* __restrict__ g, const float* __restrict__ be,
                  const float* __restrict__ skip, float* __restrict__ outP,
                  float* __restrict__ outHWC) {
  __shared__ float tile[64][65];
  __shared__ float s_sc[64], s_sh[64];
  if (threadIdx.x < 64) {
    int c = threadIdx.x;
    float sum = 0.0f, sq = 0.0f;
    for (int sl = 0; sl < NSLOT; sl++) {
      sum += stats[sl * 128 + c];
      sq  += stats[sl * 128 + 64 + c];
    }
    float m   = sum * INV_N;
    float var = sq * INV_N - m * m;
    float s   = g[c] * rsqrtf(var + EPSv);
    s_sc[c] = s;
    s_sh[c] = be[c] - m * s;
  }
  __syncthreads();
  const int blk = blockIdx.x;            // 2048 = NPIX/64
  const int b = blk >> 10;
  const int p0 = (blk & 1023) * 64;
  const float* tb = t + (size_t)b * CHW;
  const float* kb = skip + (size_t)b * CHW;
  float* oP = outP + (size_t)b * CHW;
  float* oH = outHWC + (size_t)b * CHW;
#pragma unroll
  for (int i = 0; i < 16; i++) {
    int idx = i * 256 + threadIdx.x;
    int c = idx >> 6, p = idx & 63;
    float v = fmaf(tb[c * HW + p0 + p], s_sc[c], s_sh[c]) + kb[c * HW + p0 + p];
    oP[c * HW + p0 + p] = v;
    tile[c][p] = v;
  }
  __syncthreads();
#pragma unroll
  for (int i = 0; i < 16; i++) {
    int idx = i * 256 + threadIdx.x;
    int p = idx >> 6, c = idx & 63;
    oH[(size_t)(p0 + p) * 64 + c] = tile[c][p];
  }
}

// ---------------------------------------------------------------------------
// Deformable conv on MFMA, HWC input (R9 form, measured-good): separated
// hi/lo planes, 128B rows + 32B-chunk XOR swizzle, double-buffered,
// 1 barrier/tap, __launch_bounds__(256,4) — (256,5) spills (R11: VGPR 60->48,
// 864 MB scratch traffic, 165->258 us). FINAL: fuse dc4 bias + conv4.
// ---------------------------------------------------------------------------
template <int NG, int FINAL>
__global__ __launch_bounds__(256, 4)
void dcn_mfma(const float* __restrict__ xhwc, const float* __restrict__ om,
              const ushort_t* __restrict__ wf, const float* __restrict__ bias,
              const float* __restrict__ c4w, const float* __restrict__ c4b,
              float* __restrict__ out) {
  const int tid  = threadIdx.x;
  const int lane = tid & 63, wid = tid >> 6;
  const int m = lane & 15, quad = lane >> 4;
  const int x0 = blockIdx.x * 16, y0 = blockIdx.y * 4, b = blockIdx.z;
  constexpr int WT = 2 * NG * 64 * 8;
  __shared__ __align__(16) ushort_t sh[2][64 * 64];   // hi plane per buffer, 8 KB
  __shared__ __align__(16) ushort_t sl[2][64 * 64];   // lo plane
  const int gpx = tid & 63, cg = tid >> 6;     // gather role: pixel, 16-ch group
  const int gpy = y0 + (gpx >> 4), gxx = x0 + (gpx & 15);
  const float* xb  = xhwc + (size_t)b * CHW;
  const float* omb = om + (size_t)b * 27 * HW + gpy * 256 + gxx;
  const int wchunk = (cg ^ (gpx & 3)) * 16;    // swizzled 32B-chunk base (ushorts)

  auto gather = [&](int tap, int buf) {
    float dyv = omb[tap * HW];
    float dxv = omb[(9 + tap) * HW];
    float mo  = omb[(18 + tap) * HW];
    float mk  = 1.0f / (1.0f + __expf(-mo));
    float ys = fminf(fmaxf((float)(gpy + tap / 3 - 1) + dyv, -2.0f), 258.0f);
    float xs = fminf(fmaxf((float)(gxx + tap % 3 - 1) + dxv, -2.0f), 258.0f);
    float y0f = floorf(ys), x0f = floorf(xs);
    float wy = ys - y0f, wx = xs - x0f;
    int yi = (int)y0f, xi = (int)x0f;
    float vy0 = ((unsigned)yi       < 256u) ? 1.0f : 0.0f;
    float vy1 = ((unsigned)(yi + 1) < 256u) ? 1.0f : 0.0f;
    float vx0 = ((unsigned)xi       < 256u) ? 1.0f : 0.0f;
    float vx1 = ((unsigned)(xi + 1) < 256u) ? 1.0f : 0.0f;
    int cy0 = min(max(yi, 0), 255), cy1 = min(max(yi + 1, 0), 255);
    int cx0 = min(max(xi, 0), 255), cx1 = min(max(xi + 1, 0), 255);
    float W00 = (1.0f - wy) * (1.0f - wx) * mk * vy0 * vx0;
    float W01 = (1.0f - wy) * wx * mk * vy0 * vx1;
    float W10 = wy * (1.0f - wx) * mk * vy1 * vx0;
    float W11 = wy * wx * mk * vy1 * vx1;
    const float* p00 = xb + (size_t)(cy0 * 256 + cx0) * 64 + cg * 16;
    const float* p01 = xb + (size_t)(cy0 * 256 + cx1) * 64 + cg * 16;
    const float* p10 = xb + (size_t)(cy1 * 256 + cx0) * 64 + cg * 16;
    const float* p11 = xb + (size_t)(cy1 * 256 + cx1) * 64 + cg * 16;
#pragma unroll
    for (int q4 = 0; q4 < 4; q4++) {
      float4 a  = ((const float4*)p00)[q4];
      float4 b2 = ((const float4*)p01)[q4];
      float4 c2 = ((const float4*)p10)[q4];
      float4 d2 = ((const float4*)p11)[q4];
      float s0 = W00 * a.x + W01 * b2.x + W10 * c2.x + W11 * d2.x;
      float s1 = W00 * a.y + W01 * b2.y + W10 * c2.y + W11 * d2.y;
      float s2 = W00 * a.z + W01 * b2.z + W10 * c2.z + W11 * d2.z;
      float s3 = W00 * a.w + W01 * b2.w + W10 * c2.w + W11 * d2.w;
      uint32_t h0, l0, h1, l1, h2, l2, h3, l3;
      split_hl(s0, h0, l0); split_hl(s1, h1, l1);
      split_hl(s2, h2, l2); split_hl(s3, h3, l3);
      int wi = gpx * 64 + wchunk + q4 * 4;     // 8B-aligned
      *(uint2*)&sh[buf][wi] = make_uint2(h0 | (h1 << 16), h2 | (h3 << 16));
      *(uint2*)&sl[buf][wi] = make_uint2(l0 | (l1 << 16), l2 | (l3 << 16));
    }
  };

  f32x4 acc[NG];
#pragma unroll
  for (int g = 0; g < NG; g++) acc[g] = (f32x4){0.0f, 0.0f, 0.0f, 0.0f};
  const bf16x8* wfh = (const bf16x8*)wf;
  const bf16x8* wfl = (const bf16x8*)(wf + 9 * WT);
  const int px = wid * 16 + m;                 // this lane's A-row pixel

  gather(0, 0);
  __syncthreads();
#pragma unroll 1
  for (int tap = 0; tap < 9; tap++) {
    const int cur = tap & 1;
    if (tap < 8) gather(tap + 1, cur ^ 1);     // overlaps MFMAs below
#pragma unroll
    for (int ih = 0; ih < 2; ih++) {
      const int c = ih * 2 + (quad >> 1), h = quad & 1;
      const int ri = px * 64 + ((c ^ (px & 3)) * 16) + h * 8;   // 16B-aligned
      bf16x8 ah = *(const bf16x8*)&sh[cur][ri];
      bf16x8 al = *(const bf16x8*)&sl[cur][ri];
#pragma unroll
      for (int g = 0; g < NG; g++) {
        int fi = ((tap * 2 + ih) * NG + g) * 64 + lane;
        bf16x8 bh = wfh[fi], bl = wfl[fi];
        acc[g] = __builtin_amdgcn_mfma_f32_16x16x32_bf16(ah, bh, acc[g], 0, 0, 0);
        acc[g] = __builtin_amdgcn_mfma_f32_16x16x32_bf16(al, bh, acc[g], 0, 0, 0);
        acc[g] = __builtin_amdgcn_mfma_f32_16x16x32_bf16(ah, bl, acc[g], 0, 0, 0);
      }
    }
    __syncthreads();   // writes to buf^1 and reads of cur both done
  }
  const int py = y0 + wid;
  if (FINAL) {
    if (m == 0) {
      float* op = out + (size_t)b * HW + py * 256 + x0 + quad * 4;
#pragma unroll
      for (int r = 0; r < 4; r++) op[r] = c4w[0] * (acc[0][r] + bias[0]) + c4b[0];
    }
  } else {
    float* ob = out + (size_t)b * CHW + ((size_t)py * 256 + x0 + quad * 4) * 64 + m;
#pragma unroll
    for (int g = 0; g < NG; g++)
#pragma unroll
      for (int r = 0; r < 4; r++)
        ob[r * 64 + g * 16] = fmaxf(acc[g][r] + bias[g * 16 + m], 0.0f);
  }
}

// ---------------------------------------------------------------------------
extern "C" void kernel_launch(void* const* d_in, const int* in_sizes, int n_in,
                              void* d_out, int out_size, void* d_ws, size_t ws_size,
                              hipStream_t stream) {
  const float* LowDEM    = (const float*)d_in[0];
  const float* Point_Ele = (const float*)d_in[1];
  const float* Slope     = (const float*)d_in[2];
  const float* Distance  = (const float*)d_in[3];
  const float* Level     = (const float*)d_in[4];
  const float* conv0_w   = (const float*)d_in[5];
  const float* conv0_b   = (const float*)d_in[6];
  const float* conv1_w   = (const float*)d_in[7];
  const float* conv1_b   = (const float*)d_in[8];
  const float* rb_w1     = (const float*)d_in[9];
  const float* rb_g1     = (const float*)d_in[11];
  const float* rb_be1    = (const float*)d_in[12];
  const float* rb_w2     = (const float*)d_in[13];
  const float* rb_g2     = (const float*)d_in[15];
  const float* rb_be2    = (const float*)d_in[16];
  const float* conv2_w   = (const float*)d_in[17];
  const float* bn2_g     = (const float*)d_in[19];
  const float* bn2_be    = (const float*)d_in[20];
  const float* dc2_w     = (const float*)d_in[21];
  const float* dc2_b     = (const float*)d_in[22];
  const float* dc2_ow    = (const float*)d_in[23];
  const float* dc2_ob    = (const float*)d_in[24];
  const float* dc3_w     = (const float*)d_in[25];
  const float* dc3_b     = (const float*)d_in[26];
  const float* dc3_ow    = (const float*)d_in[27];
  const float* dc3_ob    = (const float*)d_in[28];
  const float* dc4_w     = (const float*)d_in[29];
  const float* dc4_b     = (const float*)d_in[30];
  const float* dc4_ow    = (const float*)d_in[31];
  const float* dc4_ob    = (const float*)d_in[32];
  const float* conv4_w   = (const float*)d_in[33];
  const float* conv4_b   = (const float*)d_in[34];

  // small region first, then big buffers
  float* x0   = (float*)d_ws;             // 131072
  float* T1   = x0 + NPIX;                // 5184
  ushort_t* WF = (ushort_t*)(T1 + 5184);  // 39 * WFL ushorts
  float* stats = (float*)(WF + 39 * WFL); // 33 * STSLOT floats
  float* big   = stats + 33 * STSLOT;
  size_t used_small = (size_t)((char*)big - (char*)d_ws);
  bool fused = ws_size >= used_small + 5ull * NCHW * sizeof(float);

  float* bufX  = big;                     // X (conv9x9 out; skip for bn2)
  float* bufT  = bufX + NCHW;             // t1 / conv2 out / offset-conv out
  float* bufT2 = bufT + NCHW;             // t2
  float* yA    = bufT2 + NCHW;            // y ping
  float* yB    = fused ? yA + NCHW : yA;  // y pong (legacy: aliases yA)

  hipMemsetAsync(stats, 0, 33 * STSLOT * sizeof(float), stream);

  transpose_w_kernel<<<32, 256, 0, stream>>>(conv1_w, T1, 1, 64, 1, 81);

  prep_wfrag<<<dim3(144, 16), 256, 0, stream>>>(rb_w1,   WF,            4, 64, 36864, WFL);
  prep_wfrag<<<dim3(144, 16), 256, 0, stream>>>(rb_w2,   WF + 16 * WFL, 4, 64, 36864, WFL);
  prep_wfrag<<<dim3(144, 1),  256, 0, stream>>>(conv2_w, WF + 32 * WFL, 4, 64, 36864, WFL);
  prep_wfrag<<<dim3(72, 1),   256, 0, stream>>>(dc2_ow,  WF + 33 * WFL, 2, 27, 15552, WFL);
  prep_wfrag<<<dim3(72, 1),   256, 0, stream>>>(dc3_ow,  WF + 34 * WFL, 2, 27, 15552, WFL);
  prep_wfrag<<<dim3(72, 1),   256, 0, stream>>>(dc4_ow,  WF + 35 * WFL, 2, 27, 15552, WFL);
  prep_wfrag<<<dim3(144, 1),  256, 0, stream>>>(dc2_w,   WF + 36 * WFL, 4, 64, 36864, WFL);
  prep_wfrag<<<dim3(144, 1),  256, 0, stream>>>(dc3_w,   WF + 37 * WFL, 4, 64, 36864, WFL);
  prep_wfrag<<<dim3(36, 1),   256, 0, stream>>>(dc4_w,   WF + 38 * WFL, 1, 1, 576, WFL);

  prep_kernel<<<(NPIX + 255) / 256, 256, 0, stream>>>(LowDEM, Point_Ele, Slope, Distance,
                                                      Level, conv0_w, conv0_b, x0);

  dim3 grid16(16, 16, 2);   // conv9x9
  dim3 gmf(16, 64, 2);      // mfma conv3x3 / dcn_mfma (16x4 pixel tiles)

  conv9x9_kernel<<<grid16, 256, 0, stream>>>(x0, T1, conv1_b, bufX);   // X in bufX

  if (fused) {
    mfma_conv3<4, 0, 1, 64, 0, 0, 0><<<gmf, 256, 0, stream>>>(
        bufX, nullptr, WF, nullptr, nullptr, nullptr, nullptr,
        stats, nullptr, bufT);
    mfma_conv3<4, 1, 1, 64, 0, 0, 0><<<gmf, 256, 0, stream>>>(
        bufT, nullptr, WF + 16 * WFL, nullptr, stats,
        rb_g1, rb_be1, stats + STSLOT, nullptr, bufT2);
    for (int i = 1; i < 16; i++) {
      const float* skp = (i == 1) ? bufX : ((i & 1) ? yB : yA);  // y_{i-2}
      float* yo = (i & 1) ? yA : yB;                              // y_{i-1}
      mfma_conv3<4, 2, 1, 64, 0, 1, 0><<<gmf, 256, 0, stream>>>(
          bufT2, skp, WF + (size_t)i * WFL, nullptr, stats + (2 * i - 1) * STSLOT,
          rb_g2 + (i - 1) * 64, rb_be2 + (i - 1) * 64,
          stats + (2 * i) * STSLOT, yo, bufT);
      mfma_conv3<4, 1, 1, 64, 0, 0, 0><<<gmf, 256, 0, stream>>>(
          bufT, nullptr, WF + (size_t)(16 + i) * WFL, nullptr, stats + (2 * i) * STSLOT,
          rb_g1 + i * 64, rb_be1 + i * 64, stats + (2 * i + 1) * STSLOT, nullptr, bufT2);
    }
    mfma_conv3<4, 2, 1, 64, 0, 0, 0><<<gmf, 256, 0, stream>>>(
        bufT2, yA, WF + (size_t)32 * WFL, nullptr, stats + 31 * STSLOT,
        rb_g2 + 15 * 64, rb_be2 + 15 * 64, stats + 32 * STSLOT, nullptr, bufT);
  } else {
    float* bufY = yA;
    for (int i = 0; i < 16; i++) {
      const float* src = (i == 0) ? bufX : bufY;
      mfma_conv3<4, 0, 1, 64, 0, 0, 0><<<gmf, 256, 0, stream>>>(
          src, nullptr, WF + (size_t)i * WFL, nullptr, nullptr, nullptr, nullptr,
          stats + (2 * i) * STSLOT, nullptr, bufT);
      mfma_conv3<4, 1, 1, 64, 0, 0, 0><<<gmf, 256, 0, stream>>>(
          bufT, nullptr, WF + (size_t)(16 + i) * WFL, nullptr, stats + (2 * i) * STSLOT,
          rb_g1 + i * 64, rb_be1 + i * 64, stats + (2 * i + 1) * STSLOT, nullptr, bufT2);
      bn_apply_add_kernel<<<2048, 256, 0, stream>>>(bufT2, stats + (2 * i + 1) * STSLOT,
                                                    rb_g2 + i * 64, rb_be2 + i * 64, src, bufY);
    }
    mfma_conv3<4, 0, 1, 64, 0, 0, 0><<<gmf, 256, 0, stream>>>(
        bufY, nullptr, WF + (size_t)32 * WFL, nullptr, nullptr, nullptr, nullptr,
        stats + 32 * STSLOT, nullptr, bufT);
  }

  // x = bn(conv2_out) + X -> bufX (planar) AND xT (HWC) in one fused pass
  float* xT    = fused ? yB : yA;     // free by now
  float* d2out = fused ? yA : bufT2;  // dc2 output (HWC)
  float* d3out = fused ? bufT2 : yA;  // dc3 output (HWC)
  bn_tx_kernel<<<2048, 256, 0, stream>>>(bufT, stats + 32 * STSLOT, bn2_g, bn2_be,
                                         bufX, bufX, xT);

  // dc2
  mfma_conv3<2, 0, 0, 27, 1, 0, 0><<<gmf, 256, 0, stream>>>(
      bufX, nullptr, WF + (size_t)33 * WFL, dc2_ob, nullptr, nullptr, nullptr,
      nullptr, nullptr, bufT);
  dcn_mfma<4, 0><<<gmf, 256, 0, stream>>>(xT, bufT, WF + (size_t)36 * WFL, dc2_b,
                                          nullptr, nullptr, d2out);
  // dc3
  mfma_conv3<2, 0, 0, 27, 1, 0, 1><<<gmf, 256, 0, stream>>>(
      d2out, nullptr, WF + (size_t)34 * WFL, dc3_ob, nullptr, nullptr, nullptr,
      nullptr, nullptr, bufT);
  dcn_mfma<4, 0><<<gmf, 256, 0, stream>>>(d2out, bufT, WF + (size_t)37 * WFL, dc3_b,
                                          nullptr, nullptr, d3out);
  // dc4 + conv4 -> d_out
  mfma_conv3<2, 0, 0, 27, 1, 0, 1><<<gmf, 256, 0, stream>>>(
      d3out, nullptr, WF + (size_t)35 * WFL, dc4_ob, nullptr, nullptr, nullptr,
      nullptr, nullptr, bufT);
  dcn_mfma<1, 1><<<gmf, 256, 0, stream>>>(d3out, bufT, WF + (size_t)38 * WFL, dc4_b,
                                          conv4_w, conv4_b, (float*)d_out);
}

// Round 14
// 3139.762 us; speedup vs baseline: 1.1040x; 1.0379x over previous
//
#include <hip/hip_runtime.h>
#include <cmath>

typedef unsigned short ushort_t;
typedef __attribute__((ext_vector_type(8))) short bf16x8;
typedef __attribute__((ext_vector_type(4))) float f32x4;

// Problem constants (B=2, C=64, H=W=256)
static constexpr int Bn   = 2;
static constexpr int Hn   = 256;
static constexpr int Wn   = 256;
static constexpr int HW   = Hn * Wn;          // 65536
static constexpr int CHW  = 64 * HW;          // 4194304
static constexpr int NCHW = Bn * CHW;         // 8388608
static constexpr int NPIX = Bn * HW;          // 131072
static constexpr float EPSv = 1e-5f;
static constexpr float INV_N = 1.0f / 131072.0f;   // BN count = B*H*W
static constexpr int NSLOT = 64;              // stats slot replication (anti-contention)
static constexpr int STSLOT = NSLOT * 128;    // floats per layer stats region
static constexpr int WFL = 73728;             // ushorts per weight-fragment layer slot

// bf16 round-to-nearest-even (no NaN inputs in this net)
__device__ inline uint32_t bf16_rne(float f) {
  uint32_t u = __float_as_uint(f);
  return (u + 0x7FFFu + ((u >> 16) & 1u)) >> 16;
}
__device__ inline void split_hl(float v, uint32_t& h, uint32_t& l) {
  h = bf16_rne(v);
  l = bf16_rne(v - __uint_as_float(h << 16)) & 0xFFFFu;
}
__device__ inline bf16x8 lds_ld16(const ushort_t* p) {   // 2x ds_read_b64
  union { bf16x8 v; uint2 u[2]; } r;
  r.u[0] = *(const uint2*)p;
  r.u[1] = *(const uint2*)(p + 4);
  return r.v;
}

// ---------------------------------------------------------------------------
__global__ void transpose_w_kernel(const float* __restrict__ in, float* __restrict__ out,
                                   int NB, int OC, int IC, int K) {
  int total = NB * OC * IC * K;
  for (int i = blockIdx.x * blockDim.x + threadIdx.x; i < total; i += gridDim.x * blockDim.x) {
    int k  = i % K;
    int t  = i / K;
    int ic = t % IC; t /= IC;
    int oc = t % OC;
    int nb = t / OC;
    out[(((size_t)nb * IC + ic) * K + k) * OC + oc] = in[i];
  }
}

// ---------------------------------------------------------------------------
// Weight fragment prep: w[oc][ic][3][3] f32 -> MFMA B-frag order, bf16 hi/lo.
__global__ void prep_wfrag(const float* __restrict__ w, ushort_t* __restrict__ out,
                           int NGp, int ocreal, int wlstride, int olstride) {
  int layer = blockIdx.y;
  int elems = 9 * 2 * NGp * 64 * 8;
  int idx = blockIdx.x * 256 + threadIdx.x;
  if (idx >= elems) return;
  int j = idx & 7, lane = (idx >> 3) & 63;
  int rest = idx >> 9;
  int g = rest % NGp; rest /= NGp;
  int ih = rest & 1, tap = rest >> 1;
  int oc = g * 16 + (lane & 15);
  int ic = ih * 32 + (lane >> 4) * 8 + j;
  float v = 0.0f;
  if (oc < ocreal) v = w[(size_t)layer * wlstride + (oc * 64 + ic) * 9 + tap];
  uint32_t hi, lo;
  split_hl(v, hi, lo);
  out[(size_t)layer * olstride + idx] = (ushort_t)hi;
  out[(size_t)layer * olstride + elems + idx] = (ushort_t)lo;
}

// ---------------------------------------------------------------------------
__global__ void prep_kernel(const float* __restrict__ LowDEM, const float* __restrict__ Point_Ele,
                            const float* __restrict__ Slope, const float* __restrict__ Distance,
                            const float* __restrict__ Level, const float* __restrict__ w0,
                            const float* __restrict__ b0, float* __restrict__ x0) {
  int i = blockIdx.x * blockDim.x + threadIdx.x;
  if (i >= NPIX) return;
  float lv  = Level[i];
  float err = w0[0] * Slope[i] + w0[1] * Distance[i] + w0[2] * lv + b0[0];
  float lm  = (lv != 0.0f) ? 1.0f : 0.0f;
  x0[i] = LowDEM[i] * (1.0f - lm) + Point_Ele[i] + err * lm;
}

// ---------------------------------------------------------------------------
__global__ __launch_bounds__(256, 2)
void conv9x9_kernel(const float* __restrict__ in, const float* __restrict__ wT,
                    const float* __restrict__ bias, float* __restrict__ out) {
  const int tx = threadIdx.x & 15, ty = threadIdx.x >> 4;
  const int w0 = blockIdx.x * 16, h0 = blockIdx.y * 16, b = blockIdx.z;
  __shared__ float lds[24 * 24];
  for (int idx = threadIdx.x; idx < 576; idx += 256) {
    int yy = idx / 24, xx = idx - yy * 24;
    int gy = h0 + yy - 4, gx = w0 + xx - 4;
    float v = 0.0f;
    if ((unsigned)gy < 256u && (unsigned)gx < 256u) v = in[b * HW + gy * 256 + gx];
    lds[idx] = v;
  }
  __syncthreads();
  float acc[64];
#pragma unroll
  for (int o = 0; o < 64; o++) acc[o] = 0.0f;
#pragma unroll 1
  for (int i = 0; i < 9; i++) {
#pragma unroll
    for (int j = 0; j < 9; j++) {
      float v = lds[(ty + i) * 24 + tx + j];
      const float* wp = wT + (i * 9 + j) * 64;   // uniform -> s_load
#pragma unroll
      for (int o = 0; o < 64; o++) acc[o] = fmaf(v, wp[o], acc[o]);
    }
  }
  const int p = (h0 + ty) * 256 + (w0 + tx);
  float* op = out + (size_t)b * CHW + p;
#pragma unroll
  for (int o = 0; o < 64; o++) op[o * HW] = acc[o] + bias[o];
}

// ---------------------------------------------------------------------------
// MFMA conv3x3 — R14: EXACT R9 form (measured best, 3147 us total): serial
// 64-thread stats preamble (NO extra barrier before staging — the R10+
// "parallel" preamble's added __syncthreads cost ~2-3 us/dispatch x32),
// separate red buffer, bounds (256,3), separated hi/lo planes, batched
// B-loads.
// PLATEAU (R8-R13, 6 experiments): ~65 us/dispatch invariant across B-load
// batching/pipelining, A-read width, MFMA:load intensity, occupancy bounds,
// preamble parallelization. ~18% MFMA util — structural staging/barrier
// bound of this 2-phase shape, not a HW roofline.
// MODE 0 plain / 1 relu(bn) / 2 bn+skip (WRITEY: materialize y). INHWC:
// pixel-major input.
// ---------------------------------------------------------------------------
template <int NG, int MODE, int STATS, int OCLIM, int HASBIAS, int WRITEY, int INHWC>
__global__ __launch_bounds__(256, 3)
void mfma_conv3(const float* __restrict__ in, const float* __restrict__ skip,
                const ushort_t* __restrict__ wf,
                const float* __restrict__ bias, const float* __restrict__ stats_in,
                const float* __restrict__ gg, const float* __restrict__ be,
                float* __restrict__ stats_out, float* __restrict__ yout,
                float* __restrict__ out) {
  const int tid  = threadIdx.x;
  const int lane = tid & 63, wid = tid >> 6;
  const int m = lane & 15, quad = lane >> 4;
  const int x0 = blockIdx.x * 16, y0 = blockIdx.y * 4, b = blockIdx.z;
  constexpr int WT = 2 * NG * 64 * 8;          // ushorts per tap per plane
  __shared__ __align__(16) ushort_t xh[108 * 68];   // hi plane, [spat][ch]
  __shared__ __align__(16) ushort_t xl[108 * 68];   // lo plane
  __shared__ float s_sc[MODE ? 64 : 1], s_sh[MODE ? 64 : 1];
  __shared__ float red[STATS ? 2 * 4 * 64 : 1];
  if (MODE) {
    if (tid < 64) {
      float sum = 0.0f, sq = 0.0f;
      for (int sl = 0; sl < NSLOT; sl++) {
        sum += stats_in[sl * 128 + tid];
        sq  += stats_in[sl * 128 + 64 + tid];
      }
      float mn = sum * INV_N, var = sq * INV_N - mn * mn;
      float s = gg[tid] * rsqrtf(var + EPSv);
      s_sc[tid] = s;
      s_sh[tid] = be[tid] - mn * s;
    }
    __syncthreads();
  }
  const float* inb = in + (size_t)b * CHW;
  const float* skb = MODE == 2 ? skip + (size_t)b * CHW : nullptr;
  float* ytb = WRITEY ? yout + (size_t)b * CHW : nullptr;
  uint32_t* xh32 = (uint32_t*)xh;              // row stride 34 dwords
  uint32_t* xl32 = (uint32_t*)xl;
#pragma unroll
  for (int t = 0; t < 14; t++) {
    int idx = t * 256 + tid;                   // 3456 = 108 spat * 32 ic-pairs
    if (idx < 3456) {
      int r, icp;
      if (INHWC) { icp = idx & 31; r = idx >> 5; }   // tid-contig ic -> coalesced HWC
      else       { r = idx % 108; icp = idx / 108; } // tid-contig px -> coalesced NCHW
      int row = r / 18, col = r - row * 18;
      int gy = y0 - 1 + row, gx = x0 - 1 + col;
      float v0 = 0.0f, v1 = 0.0f;
      if ((unsigned)gy < 256u && (unsigned)gx < 256u) {
        int ic = icp * 2;
        if (INHWC) {
          float2 vv = *(const float2*)&inb[(size_t)(gy * 256 + gx) * 64 + ic];
          v0 = vv.x; v1 = vv.y;
        } else {
          v0 = inb[ic * HW + gy * 256 + gx];
          v1 = inb[(ic + 1) * HW + gy * 256 + gx];
        }
        if (MODE == 1) {
          v0 = fmaxf(fmaf(v0, s_sc[ic], s_sh[ic]), 0.0f);
          v1 = fmaxf(fmaf(v1, s_sc[ic + 1], s_sh[ic + 1]), 0.0f);
        }
        if (MODE == 2) {
          v0 = fmaf(v0, s_sc[ic], s_sh[ic]) + skb[ic * HW + gy * 256 + gx];
          v1 = fmaf(v1, s_sc[ic + 1], s_sh[ic + 1]) + skb[(ic + 1) * HW + gy * 256 + gx];
          if (WRITEY && row >= 1 && row <= 4 && col >= 1 && col <= 16) {
            ytb[ic * HW + gy * 256 + gx] = v0;
            ytb[(ic + 1) * HW + gy * 256 + gx] = v1;
          }
        }
      }
      uint32_t h0, l0, h1, l1;
      split_hl(v0, h0, l0);
      split_hl(v1, h1, l1);
      xh32[r * 34 + icp] = h0 | (h1 << 16);
      xl32[r * 34 + icp] = l0 | (l1 << 16);
    }
  }
  __syncthreads();                             // the ONLY barrier before epilogue
  f32x4 acc[NG];
#pragma unroll
  for (int g = 0; g < NG; g++) acc[g] = (f32x4){0.0f, 0.0f, 0.0f, 0.0f};

  const bf16x8* wfh = (const bf16x8*)wf;                 // hi plane, frag-ordered
  const bf16x8* wfl = (const bf16x8*)(wf + 9 * WT);      // lo plane

#pragma unroll 1
  for (int tap = 0; tap < 9; tap++) {
    bf16x8 bh[2][NG], bl[2][NG];
#pragma unroll
    for (int ih = 0; ih < 2; ih++)
#pragma unroll
      for (int g = 0; g < NG; g++) {
        int fi = ((tap * 2 + ih) * NG + g) * 64 + lane;
        bh[ih][g] = wfh[fi];
        bl[ih][g] = wfl[fi];
      }
    const int dy = tap / 3 - 1, dx = tap % 3 - 1;
    const int spat = (wid + dy + 1) * 18 + (m + dx + 1);
#pragma unroll
    for (int ih = 0; ih < 2; ih++) {
      const int base = spat * 68 + ih * 32 + quad * 8;
      bf16x8 ah = lds_ld16(xh + base);
      bf16x8 al = lds_ld16(xl + base);
#pragma unroll
      for (int g = 0; g < NG; g++) {
        acc[g] = __builtin_amdgcn_mfma_f32_16x16x32_bf16(ah, bh[ih][g], acc[g], 0, 0, 0);
        acc[g] = __builtin_amdgcn_mfma_f32_16x16x32_bf16(al, bh[ih][g], acc[g], 0, 0, 0);
        acc[g] = __builtin_amdgcn_mfma_f32_16x16x32_bf16(ah, bl[ih][g], acc[g], 0, 0, 0);
      }
    }
  }
  // epilogue: D[row=quad*4+r][col=lane&15] -> pixel (y0+wid, x0+quad*4+r), oc=g*16+m
  const int py = y0 + wid;
  float* ob = out + (size_t)b * OCLIM * HW + py * 256 + x0 + quad * 4;
#pragma unroll
  for (int g = 0; g < NG; g++) {
    int oc = g * 16 + m;
    if (oc < OCLIM) {
      float bv = HASBIAS ? bias[oc] : 0.0f;
#pragma unroll
      for (int r = 0; r < 4; r++) ob[oc * HW + r] = acc[g][r] + bv;
    }
    if (STATS) {
      float s  = acc[g][0] + acc[g][1] + acc[g][2] + acc[g][3];
      float s2 = acc[g][0] * acc[g][0] + acc[g][1] * acc[g][1] +
                 acc[g][2] * acc[g][2] + acc[g][3] * acc[g][3];
      s  += __shfl_xor(s, 16, 64);  s  += __shfl_xor(s, 32, 64);
      s2 += __shfl_xor(s2, 16, 64); s2 += __shfl_xor(s2, 32, 64);
      if (lane < 16) {
        red[(0 * 4 + wid) * 64 + g * 16 + lane] = s;
        red[(1 * 4 + wid) * 64 + g * 16 + lane] = s2;
      }
    }
  }
  if (STATS) {
    __syncthreads();
    if (tid < 128) {
      int oc = tid & 63, which = tid >> 6;
      float tot = red[(which * 4 + 0) * 64 + oc] + red[(which * 4 + 1) * 64 + oc] +
                  red[(which * 4 + 2) * 64 + oc] + red[(which * 4 + 3) * 64 + oc];
      int slot = (blockIdx.y * 16 + blockIdx.x) & (NSLOT - 1);
      atomicAdd(&stats_out[slot * 128 + which * 64 + oc], tot);
    }
  }
}

// ---------------------------------------------------------------------------
// Legacy path only: y = BN(t)*g+be + skip (float4).
// ---------------------------------------------------------------------------
__global__ void bn_apply_add_kernel(const float* __restrict__ t, const float* __restrict__ stats,
                                    const float* __restrict__ g, const float* __restrict__ be,
                                    const float* __restrict__ skip, float* __restrict__ out) {
  __shared__ float s_sc[64], s_sh[64];
  if (threadIdx.x < 64) {
    int c = threadIdx.x;
    float sum = 0.0f, sq = 0.0f;
    for (int sl = 0; sl < NSLOT; sl++) {
      sum += stats[sl * 128 + c];
      sq  += stats[sl * 128 + 64 + c];
    }
    float m   = sum * INV_N;
    float var = sq * INV_N - m * m;
    float s   = g[c] * rsqrtf(var + EPSv);
    s_sc[c] = s;
    s_sh[c] = be[c] - m * s;
  }
  __syncthreads();
  const float4* t4 = (const float4*)t;
  const float4* k4 = (const float4*)skip;
  float4* o4 = (float4*)out;
  const int n4 = NCHW / 4;
  for (int i = blockIdx.x * blockDim.x + threadIdx.x; i < n4; i += gridDim.x * blockDim.x) {
    int c = (i >> 14) & 63;
    float s = s_sc[c], h = s_sh[c];
    float4 v = t4[i], kk = k4[i], r;
    r.x = fmaf(v.x, s, h) + kk.x;
    r.y = fmaf(v.y, s, h) + kk.y;
    r.z = fmaf(v.z, s, h) + kk.z;
    r.w = fmaf(v.w, s, h) + kk.w;
    o4[i] = r;
  }
}

// ---------------------------------------------------------------------------
// Fused x = bn(t)+skip -> planar out AND HWC mirror in one LDS-tiled pass
// (merges bn_apply_add + nchw_to_nhwc: saves one 33 MB re-read + a launch).
// ---------------------------------------------------------------------------
__global__ __launch_bounds__(256, 4)
void bn_tx_kernel(const float* __restrict__ t, const float* __restrict__ stats,
                  const float* __restrict__ g, const float* __restrict__ be,
                  const float* __restrict__ skip, float* __restrict__ outP,
                  float* __restrict__ outHWC) {
  __shared__ float tile[64][65];
  __shared__ float s_sc[64], s_sh[64];
  if (threadIdx.x < 64) {
    int c = threadIdx.x;
    float sum = 0.0f, sq = 0.0f;
    for (int sl = 0; sl < NSLOT; sl++) {
      sum += stats[sl * 128 + c];
      sq  += stats[sl * 128 + 64 + c];
    }
    float m   = sum * INV_N;
    float var = sq * INV_N - m * m;
    float s   = g[c] * rsqrtf(var + EPSv);
    s_sc[c] = s;
    s_sh[c] = be[c] - m * s;
  }
  __syncthreads();
  const int blk = blockIdx.x;            // 2048 = NPIX/64
  const int b = blk >> 10;
  const int p0 = (blk & 1023) * 64;
  const float* tb = t + (size_t)b * CHW;
  const float* kb = skip + (size_t)b * CHW;
  float* oP = outP + (size_t)b * CHW;
  float* oH = outHWC + (size_t)b * CHW;
#pragma unroll
  for (int i = 0; i < 16; i++) {
    int idx = i * 256 + threadIdx.x;
    int c = idx >> 6, p = idx & 63;
    float v = fmaf(tb[c * HW + p0 + p], s_sc[c], s_sh[c]) + kb[c * HW + p0 + p];
    oP[c * HW + p0 + p] = v;
    tile[c][p] = v;
  }
  __syncthreads();
#pragma unroll
  for (int i = 0; i < 16; i++) {
    int idx = i * 256 + threadIdx.x;
    int p = idx >> 6, c = idx & 63;
    oH[(size_t)(p0 + p) * 64 + c] = tile[c][p];
  }
}

// ---------------------------------------------------------------------------
// Deformable conv on MFMA, HWC input (R9 form, measured-good): separated
// hi/lo planes, 128B rows + 32B-chunk XOR swizzle, double-buffered,
// 1 barrier/tap, __launch_bounds__(256,4) — (256,5) spills (R11: VGPR 60->48,
// 864 MB scratch traffic, 165->258 us). FINAL: fuse dc4 bias + conv4.
// ---------------------------------------------------------------------------
template <int NG, int FINAL>
__global__ __launch_bounds__(256, 4)
void dcn_mfma(const float* __restrict__ xhwc, const float* __restrict__ om,
              const ushort_t* __restrict__ wf, const float* __restrict__ bias,
              const float* __restrict__ c4w, const float* __restrict__ c4b,
              float* __restrict__ out) {
  const int tid  = threadIdx.x;
  const int lane = tid & 63, wid = tid >> 6;
  const int m = lane & 15, quad = lane >> 4;
  const int x0 = blockIdx.x * 16, y0 = blockIdx.y * 4, b = blockIdx.z;
  constexpr int WT = 2 * NG * 64 * 8;
  __shared__ __align__(16) ushort_t sh[2][64 * 64];   // hi plane per buffer, 8 KB
  __shared__ __align__(16) ushort_t sl[2][64 * 64];   // lo plane
  const int gpx = tid & 63, cg = tid >> 6;     // gather role: pixel, 16-ch group
  const int gpy = y0 + (gpx >> 4), gxx = x0 + (gpx & 15);
  const float* xb  = xhwc + (size_t)b * CHW;
  const float* omb = om + (size_t)b * 27 * HW + gpy * 256 + gxx;
  const int wchunk = (cg ^ (gpx & 3)) * 16;    // swizzled 32B-chunk base (ushorts)

  auto gather = [&](int tap, int buf) {
    float dyv = omb[tap * HW];
    float dxv = omb[(9 + tap) * HW];
    float mo  = omb[(18 + tap) * HW];
    float mk  = 1.0f / (1.0f + __expf(-mo));
    float ys = fminf(fmaxf((float)(gpy + tap / 3 - 1) + dyv, -2.0f), 258.0f);
    float xs = fminf(fmaxf((float)(gxx + tap % 3 - 1) + dxv, -2.0f), 258.0f);
    float y0f = floorf(ys), x0f = floorf(xs);
    float wy = ys - y0f, wx = xs - x0f;
    int yi = (int)y0f, xi = (int)x0f;
    float vy0 = ((unsigned)yi       < 256u) ? 1.0f : 0.0f;
    float vy1 = ((unsigned)(yi + 1) < 256u) ? 1.0f : 0.0f;
    float vx0 = ((unsigned)xi       < 256u) ? 1.0f : 0.0f;
    float vx1 = ((unsigned)(xi + 1) < 256u) ? 1.0f : 0.0f;
    int cy0 = min(max(yi, 0), 255), cy1 = min(max(yi + 1, 0), 255);
    int cx0 = min(max(xi, 0), 255), cx1 = min(max(xi + 1, 0), 255);
    float W00 = (1.0f - wy) * (1.0f - wx) * mk * vy0 * vx0;
    float W01 = (1.0f - wy) * wx * mk * vy0 * vx1;
    float W10 = wy * (1.0f - wx) * mk * vy1 * vx0;
    float W11 = wy * wx * mk * vy1 * vx1;
    const float* p00 = xb + (size_t)(cy0 * 256 + cx0) * 64 + cg * 16;
    const float* p01 = xb + (size_t)(cy0 * 256 + cx1) * 64 + cg * 16;
    const float* p10 = xb + (size_t)(cy1 * 256 + cx0) * 64 + cg * 16;
    const float* p11 = xb + (size_t)(cy1 * 256 + cx1) * 64 + cg * 16;
#pragma unroll
    for (int q4 = 0; q4 < 4; q4++) {
      float4 a  = ((const float4*)p00)[q4];
      float4 b2 = ((const float4*)p01)[q4];
      float4 c2 = ((const float4*)p10)[q4];
      float4 d2 = ((const float4*)p11)[q4];
      float s0 = W00 * a.x + W01 * b2.x + W10 * c2.x + W11 * d2.x;
      float s1 = W00 * a.y + W01 * b2.y + W10 * c2.y + W11 * d2.y;
      float s2 = W00 * a.z + W01 * b2.z + W10 * c2.z + W11 * d2.z;
      float s3 = W00 * a.w + W01 * b2.w + W10 * c2.w + W11 * d2.w;
      uint32_t h0, l0, h1, l1, h2, l2, h3, l3;
      split_hl(s0, h0, l0); split_hl(s1, h1, l1);
      split_hl(s2, h2, l2); split_hl(s3, h3, l3);
      int wi = gpx * 64 + wchunk + q4 * 4;     // 8B-aligned
      *(uint2*)&sh[buf][wi] = make_uint2(h0 | (h1 << 16), h2 | (h3 << 16));
      *(uint2*)&sl[buf][wi] = make_uint2(l0 | (l1 << 16), l2 | (l3 << 16));
    }
  };

  f32x4 acc[NG];
#pragma unroll
  for (int g = 0; g < NG; g++) acc[g] = (f32x4){0.0f, 0.0f, 0.0f, 0.0f};
  const bf16x8* wfh = (const bf16x8*)wf;
  const bf16x8* wfl = (const bf16x8*)(wf + 9 * WT);
  const int px = wid * 16 + m;                 // this lane's A-row pixel

  gather(0, 0);
  __syncthreads();
#pragma unroll 1
  for (int tap = 0; tap < 9; tap++) {
    const int cur = tap & 1;
    if (tap < 8) gather(tap + 1, cur ^ 1);     // overlaps MFMAs below
#pragma unroll
    for (int ih = 0; ih < 2; ih++) {
      const int c = ih * 2 + (quad >> 1), h = quad & 1;
      const int ri = px * 64 + ((c ^ (px & 3)) * 16) + h * 8;   // 16B-aligned
      bf16x8 ah = *(const bf16x8*)&sh[cur][ri];
      bf16x8 al = *(const bf16x8*)&sl[cur][ri];
#pragma unroll
      for (int g = 0; g < NG; g++) {
        int fi = ((tap * 2 + ih) * NG + g) * 64 + lane;
        bf16x8 bh = wfh[fi], bl = wfl[fi];
        acc[g] = __builtin_amdgcn_mfma_f32_16x16x32_bf16(ah, bh, acc[g], 0, 0, 0);
        acc[g] = __builtin_amdgcn_mfma_f32_16x16x32_bf16(al, bh, acc[g], 0, 0, 0);
        acc[g] = __builtin_amdgcn_mfma_f32_16x16x32_bf16(ah, bl, acc[g], 0, 0, 0);
      }
    }
    __syncthreads();   // writes to buf^1 and reads of cur both done
  }
  const int py = y0 + wid;
  if (FINAL) {
    if (m == 0) {
      float* op = out + (size_t)b * HW + py * 256 + x0 + quad * 4;
#pragma unroll
      for (int r = 0; r < 4; r++) op[r] = c4w[0] * (acc[0][r] + bias[0]) + c4b[0];
    }
  } else {
    float* ob = out + (size_t)b * CHW + ((size_t)py * 256 + x0 + quad * 4) * 64 + m;
#pragma unroll
    for (int g = 0; g < NG; g++)
#pragma unroll
      for (int r = 0; r < 4; r++)
        ob[r * 64 + g * 16] = fmaxf(acc[g][r] + bias[g * 16 + m], 0.0f);
  }
}

// ---------------------------------------------------------------------------
extern "C" void kernel_launch(void* const* d_in, const int* in_sizes, int n_in,
                              void* d_out, int out_size, void* d_ws, size_t ws_size,
                              hipStream_t stream) {
  const float* LowDEM    = (const float*)d_in[0];
  const float* Point_Ele = (const float*)d_in[1];
  const float* Slope     = (const float*)d_in[2];
  const float* Distance  = (const float*)d_in[3];
  const float* Level     = (const float*)d_in[4];
  const float* conv0_w   = (const float*)d_in[5];
  const float* conv0_b   = (const float*)d_in[6];
  const float* conv1_w   = (const float*)d_in[7];
  const float* conv1_b   = (const float*)d_in[8];
  const float* rb_w1     = (const float*)d_in[9];
  const float* rb_g1     = (const float*)d_in[11];
  const float* rb_be1    = (const float*)d_in[12];
  const float* rb_w2     = (const float*)d_in[13];
  const float* rb_g2     = (const float*)d_in[15];
  const float* rb_be2    = (const float*)d_in[16];
  const float* conv2_w   = (const float*)d_in[17];
  const float* bn2_g     = (const float*)d_in[19];
  const float* bn2_be    = (const float*)d_in[20];
  const float* dc2_w     = (const float*)d_in[21];
  const float* dc2_b     = (const float*)d_in[22];
  const float* dc2_ow    = (const float*)d_in[23];
  const float* dc2_ob    = (const float*)d_in[24];
  const float* dc3_w     = (const float*)d_in[25];
  const float* dc3_b     = (const float*)d_in[26];
  const float* dc3_ow    = (const float*)d_in[27];
  const float* dc3_ob    = (const float*)d_in[28];
  const float* dc4_w     = (const float*)d_in[29];
  const float* dc4_b     = (const float*)d_in[30];
  const float* dc4_ow    = (const float*)d_in[31];
  const float* dc4_ob    = (const float*)d_in[32];
  const float* conv4_w   = (const float*)d_in[33];
  const float* conv4_b   = (const float*)d_in[34];

  // small region first, then big buffers
  float* x0   = (float*)d_ws;             // 131072
  float* T1   = x0 + NPIX;                // 5184
  ushort_t* WF = (ushort_t*)(T1 + 5184);  // 39 * WFL ushorts
  float* stats = (float*)(WF + 39 * WFL); // 33 * STSLOT floats
  float* big   = stats + 33 * STSLOT;
  size_t used_small = (size_t)((char*)big - (char*)d_ws);
  bool fused = ws_size >= used_small + 5ull * NCHW * sizeof(float);

  float* bufX  = big;                     // X (conv9x9 out; skip for bn2)
  float* bufT  = bufX + NCHW;             // t1 / conv2 out / offset-conv out
  float* bufT2 = bufT + NCHW;             // t2
  float* yA    = bufT2 + NCHW;            // y ping
  float* yB    = fused ? yA + NCHW : yA;  // y pong (legacy: aliases yA)

  hipMemsetAsync(stats, 0, 33 * STSLOT * sizeof(float), stream);

  transpose_w_kernel<<<32, 256, 0, stream>>>(conv1_w, T1, 1, 64, 1, 81);

  prep_wfrag<<<dim3(144, 16), 256, 0, stream>>>(rb_w1,   WF,            4, 64, 36864, WFL);
  prep_wfrag<<<dim3(144, 16), 256, 0, stream>>>(rb_w2,   WF + 16 * WFL, 4, 64, 36864, WFL);
  prep_wfrag<<<dim3(144, 1),  256, 0, stream>>>(conv2_w, WF + 32 * WFL, 4, 64, 36864, WFL);
  prep_wfrag<<<dim3(72, 1),   256, 0, stream>>>(dc2_ow,  WF + 33 * WFL, 2, 27, 15552, WFL);
  prep_wfrag<<<dim3(72, 1),   256, 0, stream>>>(dc3_ow,  WF + 34 * WFL, 2, 27, 15552, WFL);
  prep_wfrag<<<dim3(72, 1),   256, 0, stream>>>(dc4_ow,  WF + 35 * WFL, 2, 27, 15552, WFL);
  prep_wfrag<<<dim3(144, 1),  256, 0, stream>>>(dc2_w,   WF + 36 * WFL, 4, 64, 36864, WFL);
  prep_wfrag<<<dim3(144, 1),  256, 0, stream>>>(dc3_w,   WF + 37 * WFL, 4, 64, 36864, WFL);
  prep_wfrag<<<dim3(36, 1),   256, 0, stream>>>(dc4_w,   WF + 38 * WFL, 1, 1, 576, WFL);

  prep_kernel<<<(NPIX + 255) / 256, 256, 0, stream>>>(LowDEM, Point_Ele, Slope, Distance,
                                                      Level, conv0_w, conv0_b, x0);

  dim3 grid16(16, 16, 2);   // conv9x9
  dim3 gmf(16, 64, 2);      // mfma conv3x3 / dcn_mfma (16x4 pixel tiles)

  conv9x9_kernel<<<grid16, 256, 0, stream>>>(x0, T1, conv1_b, bufX);   // X in bufX

  if (fused) {
    mfma_conv3<4, 0, 1, 64, 0, 0, 0><<<gmf, 256, 0, stream>>>(
        bufX, nullptr, WF, nullptr, nullptr, nullptr, nullptr,
        stats, nullptr, bufT);
    mfma_conv3<4, 1, 1, 64, 0, 0, 0><<<gmf, 256, 0, stream>>>(
        bufT, nullptr, WF + 16 * WFL, nullptr, stats,
        rb_g1, rb_be1, stats + STSLOT, nullptr, bufT2);
    for (int i = 1; i < 16; i++) {
      const float* skp = (i == 1) ? bufX : ((i & 1) ? yB : yA);  // y_{i-2}
      float* yo = (i & 1) ? yA : yB;                              // y_{i-1}
      mfma_conv3<4, 2, 1, 64, 0, 1, 0><<<gmf, 256, 0, stream>>>(
          bufT2, skp, WF + (size_t)i * WFL, nullptr, stats + (2 * i - 1) * STSLOT,
          rb_g2 + (i - 1) * 64, rb_be2 + (i - 1) * 64,
          stats + (2 * i) * STSLOT, yo, bufT);
      mfma_conv3<4, 1, 1, 64, 0, 0, 0><<<gmf, 256, 0, stream>>>(
          bufT, nullptr, WF + (size_t)(16 + i) * WFL, nullptr, stats + (2 * i) * STSLOT,
          rb_g1 + i * 64, rb_be1 + i * 64, stats + (2 * i + 1) * STSLOT, nullptr, bufT2);
    }
    mfma_conv3<4, 2, 1, 64, 0, 0, 0><<<gmf, 256, 0, stream>>>(
        bufT2, yA, WF + (size_t)32 * WFL, nullptr, stats + 31 * STSLOT,
        rb_g2 + 15 * 64, rb_be2 + 15 * 64, stats + 32 * STSLOT, nullptr, bufT);
  } else {
    float* bufY = yA;
    for (int i = 0; i < 16; i++) {
      const float* src = (i == 0) ? bufX : bufY;
      mfma_conv3<4, 0, 1, 64, 0, 0, 0><<<gmf, 256, 0, stream>>>(
          src, nullptr, WF + (size_t)i * WFL, nullptr, nullptr, nullptr, nullptr,
          stats + (2 * i) * STSLOT, nullptr, bufT);
      mfma_conv3<4, 1, 1, 64, 0, 0, 0><<<gmf, 256, 0, stream>>>(
          bufT, nullptr, WF + (size_t)(16 + i) * WFL, nullptr, stats + (2 * i) * STSLOT,
          rb_g1 + i * 64, rb_be1 + i * 64, stats + (2 * i + 1) * STSLOT, nullptr, bufT2);
      bn_apply_add_kernel<<<2048, 256, 0, stream>>>(bufT2, stats + (2 * i + 1) * STSLOT,
                                                    rb_g2 + i * 64, rb_be2 + i * 64, src, bufY);
    }
    mfma_conv3<4, 0, 1, 64, 0, 0, 0><<<gmf, 256, 0, stream>>>(
        bufY, nullptr, WF + (size_t)32 * WFL, nullptr, nullptr, nullptr, nullptr,
        stats + 32 * STSLOT, nullptr, bufT);
  }

  // x = bn(conv2_out) + X -> bufX (planar) AND xT (HWC) in one fused pass
  float* xT    = fused ? yB : yA;     // free by now
  float* d2out = fused ? yA : bufT2;  // dc2 output (HWC)
  float* d3out = fused ? bufT2 : yA;  // dc3 output (HWC)
  bn_tx_kernel<<<2048, 256, 0, stream>>>(bufT, stats + 32 * STSLOT, bn2_g, bn2_be,
                                         bufX, bufX, xT);

  // dc2
  mfma_conv3<2, 0, 0, 27, 1, 0, 0><<<gmf, 256, 0, stream>>>(
      bufX, nullptr, WF + (size_t)33 * WFL, dc2_ob, nullptr, nullptr, nullptr,
      nullptr, nullptr, bufT);
  dcn_mfma<4, 0><<<gmf, 256, 0, stream>>>(xT, bufT, WF + (size_t)36 * WFL, dc2_b,
                                          nullptr, nullptr, d2out);
  // dc3
  mfma_conv3<2, 0, 0, 27, 1, 0, 1><<<gmf, 256, 0, stream>>>(
      d2out, nullptr, WF + (size_t)34 * WFL, dc3_ob, nullptr, nullptr, nullptr,
      nullptr, nullptr, bufT);
  dcn_mfma<4, 0><<<gmf, 256, 0, stream>>>(d2out, bufT, WF + (size_t)37 * WFL, dc3_b,
                                          nullptr, nullptr, d3out);
  // dc4 + conv4 -> d_out
  mfma_conv3<2, 0, 0, 27, 1, 0, 1><<<gmf, 256, 0, stream>>>(
      d3out, nullptr, WF + (size_t)35 * WFL, dc4_ob, nullptr, nullptr, nullptr,
      nullptr, nullptr, bufT);
  dcn_mfma<1, 1><<<gmf, 256, 0, stream>>>(d3out, bufT, WF + (size_t)38 * WFL, dc4_b,
                                          conv4_w, conv4_b, (float*)d_out);
}